// Round 11
// baseline (462.955 us; speedup 1.0000x reference)
//
#include <hip/hip_runtime.h>
#include <math.h>

#define NN 100000
#define EE 1600000
#define GG 256
#define HH 128
#define BSH 8                 /* 256 nodes per bucket */
#define NBK 391               /* ceil(NN/256) */
#define PASSA_WG 1563         /* ceil(EE/1024): 4 edges/thread for occupancy */
#define CAPB 6144             /* per-bucket region: edges(~4092) + self/pad8(<=2048) */

typedef __attribute__((ext_vector_type(8))) short short8;   // 8 bf16 (4 VGPRs)
typedef __attribute__((ext_vector_type(4))) float f32x4;    // MFMA acc

union U4S8 { uint4 u; short8 s; };

// ---------------------------------------------------------------------------
// bf16 helpers (RNE pack, cheap unpack)
// ---------------------------------------------------------------------------
static __device__ __forceinline__ unsigned bf16rne(float f) {
    const unsigned u = __float_as_uint(f);
    return (u + 0x7fffu + ((u >> 16) & 1u)) >> 16;
}
static __device__ __forceinline__ unsigned packbf(float a, float b) {
    return bf16rne(a) | (bf16rne(b) << 16);
}
static __device__ __forceinline__ float bflo(unsigned u) { return __uint_as_float(u << 16); }
static __device__ __forceinline__ float bfhi(unsigned u) { return __uint_as_float(u & 0xffff0000u); }

// ---------------------------------------------------------------------------
// Fused setup: wprep (ids 0..24575), bnprep (..24703), cursinit (..25094),
// psum zero (..57862), gcnt zero (..58118), dtype detect (id 58119).
// Replaces 4 kernels + 2 memsets with one dispatch.
// ---------------------------------------------------------------------------
__global__ __launch_bounds__(256) void setup_k(
    const int* __restrict__ ei, const int* __restrict__ batch,
    const float* __restrict__ w1, const float* __restrict__ w2,
    const float* __restrict__ w3,
    const float* __restrict__ b1, const float* __restrict__ g1,
    const float* __restrict__ be1, const float* __restrict__ m1,
    const float* __restrict__ v1,
    const float* __restrict__ b2, const float* __restrict__ g2,
    const float* __restrict__ be2, const float* __restrict__ m2,
    const float* __restrict__ v2,
    const float* __restrict__ b3, const float* __restrict__ g3,
    const float* __restrict__ be3, const float* __restrict__ m3,
    const float* __restrict__ v3,
    unsigned* __restrict__ bt, float* __restrict__ sc, float* __restrict__ sh,
    int* __restrict__ cursor, float* __restrict__ psum, int* __restrict__ gcnt,
    int* __restrict__ flags) {
    const int id = blockIdx.x * 256 + threadIdx.x;
    if (id < 24576) {
        const int w = id >> 13;
        const int rem = id & 8191;
        const int n = rem >> 6;
        const int kk = rem & 63;                      // k-pair
        const float* W = (w == 0) ? w1 : (w == 1) ? w2 : w3;
        bt[id] = packbf(W[(2 * kk) * HH + n], W[(2 * kk + 1) * HH + n]);
    } else if (id < 24704) {
        const int c = id - 24576;
        float s;
        s = g1[c] / sqrtf(v1[c] + 1e-5f);
        sc[c] = s;           sh[c] = (b1[c] - m1[c]) * s + be1[c];
        s = g2[c] / sqrtf(v2[c] + 1e-5f);
        sc[128 + c] = s;     sh[128 + c] = (b2[c] - m2[c]) * s + be2[c];
        s = g3[c] / sqrtf(v3[c] + 1e-5f);
        sc[256 + c] = s;     sh[256 + c] = (b3[c] - m3[c]) * s + be3[c];
    } else if (id < 25095) {
        const int b = id - 24704;
        cursor[b] = b * CAPB;
    } else if (id < 57863) {
        psum[id - 25095] = 0.0f;
    } else if (id < 58119) {
        gcnt[id - 57863] = 0;
    } else if (id == 58119) {
        int e64 = 1;
        for (int j = 0; j < 8; ++j) {
            if (ei[2 * EE - 1 - 2 * j] != 0) { e64 = 0; break; }
        }
        flags[0] = e64;
        flags[1] = (batch[NN - 1] == 0) ? 1 : 0;
    }
}
#define SETUP_GRID 228   /* ceil(58120/256) */

// ---------------------------------------------------------------------------
// pass A: bucket-grouped packed-pair scatter into fixed regions.
// packed = (dloc<<17) | src.  1563 wgs x 1024 edges (4/thread) so ~6
// blocks/CU hide the edge-read latency (391-wg version was 1.5/CU).
// ---------------------------------------------------------------------------
__global__ __launch_bounds__(256) void passA_k(const int* __restrict__ ei,
                                               const int* __restrict__ flags,
                                               int* __restrict__ cursor,
                                               unsigned* __restrict__ pairs) {
    __shared__ int h[NBK];
    __shared__ int rbase[NBK];
    const int tid = threadIdx.x;
    for (int i = tid; i < NBK; i += 256) h[i] = 0;
    __syncthreads();
    const bool e64 = flags[0] != 0;
    const int base = blockIdx.x * 1024;
    int scache[4], dcache[4];
#pragma unroll
    for (int j = 0; j < 4; ++j) {
        const int e = base + j * 256 + tid;
        int s = -1, d = 0;
        if (e < EE) {
            s = e64 ? ei[2 * e] : ei[e];
            d = e64 ? ei[2 * (EE + e)] : ei[EE + e];
            atomicAdd(&h[d >> BSH], 1);
        }
        scache[j] = s; dcache[j] = d;
    }
    __syncthreads();
    for (int i = tid; i < NBK; i += 256) {
        const int c = h[i];
        rbase[i] = c ? atomicAdd(&cursor[i], c) : 0;
    }
    __syncthreads();
    for (int i = tid; i < NBK; i += 256) h[i] = 0;
    __syncthreads();
#pragma unroll
    for (int j = 0; j < 4; ++j) {
        const int s = scache[j];
        if (s >= 0) {
            const int d = dcache[j];
            const int b = d >> BSH;
            const int r = atomicAdd(&h[b], 1);
            pairs[rbase[b] + r] = ((unsigned)(d & 255) << 17) | (unsigned)s;
        }
    }
}

// ---------------------------------------------------------------------------
// pass B: one wg per bucket -> offs/degcnt/dinv + bucketed CSR with
// self-inclusive padding: each node's list = [edges..., self, NN-sentinels]
// padded to a multiple of 8 (sentinel NN = zero row in hpre).
// ---------------------------------------------------------------------------
__global__ __launch_bounds__(256) void passB_k(const unsigned* __restrict__ pairs,
                                               const int* __restrict__ cursor,
                                               int* __restrict__ offs,
                                               int* __restrict__ degcnt,
                                               float* __restrict__ dinv,
                                               int* __restrict__ csr) {
    __shared__ unsigned pk[CAPB];
    __shared__ int cnt[256];
    __shared__ int loff[256];
    __shared__ int sc[256];
    const int tid = threadIdx.x;
    const int b = blockIdx.x;
    const int p0 = b * CAPB;
    const int np = cursor[b] - p0;           // real edges in bucket
    const int nb0 = b << BSH;
    const int nnode = (NN - nb0 < 256) ? (NN - nb0) : 256;

    cnt[tid] = 0;
    __syncthreads();
    for (int i = tid; i < np; i += 256) {
        const unsigned p = pairs[p0 + i];
        pk[i] = p;
        atomicAdd(&cnt[p >> 17], 1);
    }
    __syncthreads();
    const int creal = cnt[tid];
    const int cpad = (tid < nnode) ? ((creal + 8) & ~7) : 0;   // +self, pad to 8
    sc[tid] = cpad;
    __syncthreads();
    for (int off = 1; off < 256; off <<= 1) {
        int t = (tid >= off) ? sc[tid - off] : 0;
        __syncthreads();
        sc[tid] += t;
        __syncthreads();
    }
    const int ex = sc[tid] - cpad;
    loff[tid] = ex;
    if (tid < nnode) {
        const int node = nb0 + tid;
        offs[node] = p0 + ex;
        degcnt[node] = creal;
        dinv[node] = 1.0f / sqrtf((float)(creal + 1));
    }
    __syncthreads();
    cnt[tid] = 0;
    __syncthreads();
    for (int i = tid; i < np; i += 256) {
        const unsigned p = pk[i];
        const int dl = (int)(p >> 17);
        const int r = atomicAdd(&cnt[dl], 1);
        csr[p0 + loff[dl] + r] = (int)(p & 0x1FFFFu);
    }
    // pad slots [creal, cpad): self then sentinels (disjoint from scatter slots)
    if (tid < nnode) {
        const int basep = p0 + loff[tid];
        csr[basep + creal] = nb0 + tid;
        for (int j = creal + 1; j < cpad; ++j) csr[basep + j] = NN;
    }
}

// ---------------------------------------------------------------------------
// Hybrid MFMA bf16 GEMM (LDS-staged B^T + direct C^T stores), verified r10.
// Row M (sentinel) is written as zeros. dinv row-scale fused.
// ---------------------------------------------------------------------------
static __device__ __forceinline__ float sani(float v) {
    if (isnan(v)) return 0.0f;
    if (isinf(v)) return v > 0.0f ? 1e6f : -1e6f;
    return v;
}

template <bool AF32>
__global__ __launch_bounds__(256) void gemm_mfma_k(const float* __restrict__ Af,
                                                   const unsigned* __restrict__ Abf,
                                                   const unsigned* __restrict__ btg,
                                                   const float* __restrict__ dinv,
                                                   unsigned* __restrict__ C, int M) {
    __shared__ unsigned lds_u[8704];   // B^T: 128 rows x 68 uints (34816 B)
    const int tid = threadIdx.x;
    const int wave = tid >> 6;
    const int lane = tid & 63;
    const int nl = lane & 15;          // node-row within wave strip / B-op column
    const int q = lane >> 4;           // k-quad
    const int row0 = blockIdx.x * 64 + wave * 16;
    const int rowg = row0 + nl;
    const int rowa = min(rowg, M - 1);

    // stage B^T: 128 rows x 64 uints (btg) -> LDS rows of 68 uints
    {
        const uint4* __restrict__ bg4 = (const uint4*)btg;
        for (int i = tid; i < 2048; i += 256) {
            const int n = i >> 4, w4 = i & 15;
            *(uint4*)&lds_u[n * 68 + w4 * 4] = bg4[n * 16 + w4];
        }
    }

    // B-operand = A rows: lane holds A[rowa][ks*32 + q*8 .. +7], 4 k-steps
    short8 a[4];
    if (AF32) {
#pragma unroll
        for (int ks = 0; ks < 4; ++ks) {
            const float4 p = *(const float4*)(Af + (size_t)rowa * HH + ks * 32 + q * 8);
            const float4 r = *(const float4*)(Af + (size_t)rowa * HH + ks * 32 + q * 8 + 4);
            U4S8 cv;
            cv.u = make_uint4(packbf(sani(p.x), sani(p.y)), packbf(sani(p.z), sani(p.w)),
                              packbf(sani(r.x), sani(r.y)), packbf(sani(r.z), sani(r.w)));
            a[ks] = cv.s;
        }
    } else {
#pragma unroll
        for (int ks = 0; ks < 4; ++ks) {
            U4S8 cv;
            cv.u = *(const uint4*)(Abf + (size_t)rowa * 64 + ks * 16 + q * 4);
            a[ks] = cv.s;
        }
    }

    __syncthreads();   // B^T staged

    f32x4 acc[8];
#pragma unroll
    for (int t = 0; t < 8; ++t) acc[t] = (f32x4)0.0f;

    // A-operand = B^T fragments from LDS (ushort row stride 136)
    const unsigned short* __restrict__ bts = (const unsigned short*)lds_u;
#pragma unroll
    for (int ks = 0; ks < 4; ++ks) {
#pragma unroll
        for (int t = 0; t < 8; ++t) {
            const int n = t * 16 + nl;
            const short8 b = *(const short8*)(bts + n * 136 + ks * 32 + q * 8);
            acc[t] = __builtin_amdgcn_mfma_f32_16x16x32_bf16(b, a[ks], acc[t], 0, 0, 0);
        }
    }

    // store C^T fragments: lane holds channels t*16 + q*4 + (0..3) of node rowg
    if (rowg < M) {
        const float dsc = dinv[rowg];
        unsigned* crow = C + (size_t)rowg * 64;
#pragma unroll
        for (int t = 0; t < 8; ++t) {
            uint2 o;
            o.x = packbf(dsc * acc[t][0], dsc * acc[t][1]);
            o.y = packbf(dsc * acc[t][2], dsc * acc[t][3]);
            *(uint2*)(crow + t * 8 + q * 2) = o;
        }
    } else if (rowg == M) {
        unsigned* crow = C + (size_t)M * 64;
#pragma unroll
        for (int t = 0; t < 8; ++t)
            *(uint2*)(crow + t * 8 + q * 2) = make_uint2(0u, 0u);
    }
}

// ---------------------------------------------------------------------------
// Fused aggregate + BN(eval) + ReLU over pre-scaled rows; bf16 in/out.
// List is self-inclusive, padded to x8 with zero-row sentinels: inner loop
// is pure gather+add with 4 gathers in flight per lane.
// ---------------------------------------------------------------------------
__global__ __launch_bounds__(256) void aggregate_k(
    const unsigned* __restrict__ hpre, const int* __restrict__ csr,
    const int* __restrict__ offs, const int* __restrict__ cnt,
    const float* __restrict__ dinv,
    const float* __restrict__ bnsc, const float* __restrict__ bnsh,
    unsigned* __restrict__ xout) {
    const int v = __builtin_amdgcn_readfirstlane(blockIdx.x * 4 + (threadIdx.x >> 6));
    const int lane = threadIdx.x & 63;
    const int cg = lane & 15;
    const int sub = lane >> 4;
    const int c8 = cg * 8;

    const float dv = dinv[v];
    const int start = offs[v];
    const int npad = (cnt[v] + 8) & ~7;      // +self, padded to x8 (matches passB)
    const char* __restrict__ hb = (const char*)hpre;   // row = 256 B
    const unsigned cgo = (unsigned)(cg << 4);

    float acc[8];
#pragma unroll
    for (int j = 0; j < 8; ++j) acc[j] = 0.0f;

    int i = 0;
    for (; i + 16 <= npad; i += 16) {        // 16 entries/iter: 4 gathers in flight
        const int sA = csr[start + i + sub];
        const int sB = csr[start + i + 4 + sub];
        const int sC = csr[start + i + 8 + sub];
        const int sD = csr[start + i + 12 + sub];
        const uint4 rA = *(const uint4*)(hb + (((unsigned)sA << 8) | cgo));
        const uint4 rB = *(const uint4*)(hb + (((unsigned)sB << 8) | cgo));
        const uint4 rC = *(const uint4*)(hb + (((unsigned)sC << 8) | cgo));
        const uint4 rD = *(const uint4*)(hb + (((unsigned)sD << 8) | cgo));
        acc[0] += (bflo(rA.x) + bflo(rB.x)) + (bflo(rC.x) + bflo(rD.x));
        acc[1] += (bfhi(rA.x) + bfhi(rB.x)) + (bfhi(rC.x) + bfhi(rD.x));
        acc[2] += (bflo(rA.y) + bflo(rB.y)) + (bflo(rC.y) + bflo(rD.y));
        acc[3] += (bfhi(rA.y) + bfhi(rB.y)) + (bfhi(rC.y) + bfhi(rD.y));
        acc[4] += (bflo(rA.z) + bflo(rB.z)) + (bflo(rC.z) + bflo(rD.z));
        acc[5] += (bfhi(rA.z) + bfhi(rB.z)) + (bfhi(rC.z) + bfhi(rD.z));
        acc[6] += (bflo(rA.w) + bflo(rB.w)) + (bflo(rC.w) + bflo(rD.w));
        acc[7] += (bfhi(rA.w) + bfhi(rB.w)) + (bfhi(rC.w) + bfhi(rD.w));
    }
    if (i < npad) {                          // wave-uniform tail of exactly 8
        const int sA = csr[start + i + sub];
        const int sB = csr[start + i + 4 + sub];
        const uint4 rA = *(const uint4*)(hb + (((unsigned)sA << 8) | cgo));
        const uint4 rB = *(const uint4*)(hb + (((unsigned)sB << 8) | cgo));
        acc[0] += bflo(rA.x) + bflo(rB.x);
        acc[1] += bfhi(rA.x) + bfhi(rB.x);
        acc[2] += bflo(rA.y) + bflo(rB.y);
        acc[3] += bfhi(rA.y) + bfhi(rB.y);
        acc[4] += bflo(rA.z) + bflo(rB.z);
        acc[5] += bfhi(rA.z) + bfhi(rB.z);
        acc[6] += bflo(rA.w) + bflo(rB.w);
        acc[7] += bfhi(rA.w) + bfhi(rB.w);
    }

#pragma unroll
    for (int j = 0; j < 8; ++j) {
        acc[j] += __shfl_xor(acc[j], 16);
        acc[j] += __shfl_xor(acc[j], 32);
    }

    if (sub == 0) {
        const float4 sca = *(const float4*)(bnsc + c8);
        const float4 scb = *(const float4*)(bnsc + c8 + 4);
        const float4 sha = *(const float4*)(bnsh + c8);
        const float4 shb = *(const float4*)(bnsh + c8 + 4);
        const float y0 = fmaxf(dv * acc[0] * sca.x + sha.x, 0.0f);
        const float y1 = fmaxf(dv * acc[1] * sca.y + sha.y, 0.0f);
        const float y2 = fmaxf(dv * acc[2] * sca.z + sha.z, 0.0f);
        const float y3 = fmaxf(dv * acc[3] * sca.w + sha.w, 0.0f);
        const float y4 = fmaxf(dv * acc[4] * scb.x + shb.x, 0.0f);
        const float y5 = fmaxf(dv * acc[5] * scb.y + shb.y, 0.0f);
        const float y6 = fmaxf(dv * acc[6] * scb.z + shb.z, 0.0f);
        const float y7 = fmaxf(dv * acc[7] * scb.w + shb.w, 0.0f);
        *(uint4*)(xout + (size_t)v * 64 + cg * 4) =
            make_uint4(packbf(y0, y1), packbf(y2, y3), packbf(y4, y5), packbf(y6, y7));
    }
}

// ---------------------------------------------------------------------------
// Parallel mean-pool, phase 1: per-wave 16-row run accumulation + boundary
// atomics into psum[g][128] (f32) and gcnt[g]. batch is sorted.
// ---------------------------------------------------------------------------
__global__ __launch_bounds__(256) void pool_sum_k(
    const unsigned* __restrict__ x, const int* __restrict__ batch,
    const int* __restrict__ flags, float* __restrict__ psum,
    int* __restrict__ gcnt) {
    const int wave = threadIdx.x >> 6;
    const int lane = threadIdx.x & 63;
    const int row0 = blockIdx.x * 64 + wave * 16;
    if (row0 >= NN) return;
    const bool b64 = flags[1] != 0;

    float sx = 0.0f, sy = 0.0f;
    int cur = -1, runlen = 0;
#pragma unroll
    for (int r = 0; r < 16; ++r) {
        const int row = row0 + r;
        if (row >= NN) break;
        const int g = b64 ? batch[2 * row] : batch[row];
        if (g != cur) {
            if (cur >= 0) {
                atomicAdd(&psum[cur * HH + lane * 2 + 0], sx);
                atomicAdd(&psum[cur * HH + lane * 2 + 1], sy);
                if (lane == 0) atomicAdd(&gcnt[cur], runlen);
            }
            cur = g; sx = 0.0f; sy = 0.0f; runlen = 0;
        }
        const unsigned u = x[(size_t)row * 64 + lane];
        sx += bflo(u);
        sy += bfhi(u);
        ++runlen;
    }
    if (cur >= 0) {
        atomicAdd(&psum[cur * HH + lane * 2 + 0], sx);
        atomicAdd(&psum[cur * HH + lane * 2 + 1], sy);
        if (lane == 0) atomicAdd(&gcnt[cur], runlen);
    }
}

// ---------------------------------------------------------------------------
// Head: pooled = psum/cnt, then fc1+ReLU+fc2. One block per graph.
// ---------------------------------------------------------------------------
__global__ __launch_bounds__(128) void head_k(
    const float* __restrict__ psum, const int* __restrict__ gcnt,
    const float* __restrict__ fw1, const float* __restrict__ fb1,
    const float* __restrict__ fw2, const float* __restrict__ fb2,
    float* __restrict__ out) {
    __shared__ float pooled[128];
    __shared__ float hid[64];
    const int g = blockIdx.x;
    const int tid = threadIdx.x;

    const int cntn = gcnt[g];
    pooled[tid] = psum[g * HH + tid] / (float)(cntn > 0 ? cntn : 1);
    __syncthreads();

    if (tid < 64) {
        float a = fb1[tid];
#pragma unroll 4
        for (int k = 0; k < 128; ++k) a += pooled[k] * fw1[k * 64 + tid];
        hid[tid] = fmaxf(a, 0.0f);
    }
    __syncthreads();
    if (tid < 10) {
        float a = fb2[tid];
#pragma unroll
        for (int k = 0; k < 64; ++k) a += hid[k] * fw2[k * 10 + tid];
        out[g * 10 + tid] = a;
    }
}

// ---------------------------------------------------------------------------
// launch
// ---------------------------------------------------------------------------
extern "C" void kernel_launch(void* const* d_in, const int* in_sizes, int n_in,
                              void* d_out, int out_size, void* d_ws, size_t ws_size,
                              hipStream_t stream) {
    const float* x_in  = (const float*)d_in[0];
    const int*   ei    = (const int*)d_in[1];
    const int*   batch = (const int*)d_in[2];
    const float* w1 = (const float*)d_in[3];
    const float* b1 = (const float*)d_in[4];
    const float* w2 = (const float*)d_in[5];
    const float* b2 = (const float*)d_in[6];
    const float* w3 = (const float*)d_in[7];
    const float* b3 = (const float*)d_in[8];
    const float* g1 = (const float*)d_in[9];
    const float* be1 = (const float*)d_in[10];
    const float* m1 = (const float*)d_in[11];
    const float* v1 = (const float*)d_in[12];
    const float* g2 = (const float*)d_in[13];
    const float* be2 = (const float*)d_in[14];
    const float* m2 = (const float*)d_in[15];
    const float* v2 = (const float*)d_in[16];
    const float* g3 = (const float*)d_in[17];
    const float* be3 = (const float*)d_in[18];
    const float* m3 = (const float*)d_in[19];
    const float* v3 = (const float*)d_in[20];
    const float* fw1 = (const float*)d_in[21];
    const float* fb1 = (const float*)d_in[22];
    const float* fw2 = (const float*)d_in[23];
    const float* fb2 = (const float*)d_in[24];
    float* out = (float*)d_out;

    size_t off = 0;
    char* base = (char*)d_ws;
    auto alloc = [&](size_t bytes) -> void* {
        void* p = base + off;
        off += (bytes + 255) & ~(size_t)255;
        return p;
    };
    int*      degcnt = (int*)alloc((size_t)NN * 4);
    float*    dinv   = (float*)alloc((size_t)NN * 4);
    int*      offs   = (int*)alloc((size_t)NN * 4);
    int*      cursor = (int*)alloc((size_t)NBK * 4);
    int*      flags  = (int*)alloc(256);
    float*    bnsc   = (float*)alloc(3 * 128 * 4);
    float*    bnsh   = (float*)alloc(3 * 128 * 4);
    unsigned* btg    = (unsigned*)alloc(3 * 8192 * 4);            // bf16 B^T x3
    float*    psum   = (float*)alloc((size_t)GG * HH * 4);        // pooled sums f32
    int*      gcnt   = (int*)alloc((size_t)GG * 4);
    int*      csr    = (int*)alloc((size_t)NBK * CAPB * 4);
    unsigned* pairs  = (unsigned*)alloc((size_t)NBK * CAPB * 4);
    unsigned* bufx   = (unsigned*)alloc((size_t)NN * 64 * 4);         // bf16 x2 packed
    unsigned* hpre   = (unsigned*)alloc((size_t)(NN + 1) * 64 * 4);   // + sentinel row
    if (off > ws_size) return;

    setup_k<<<SETUP_GRID, 256, 0, stream>>>(ei, batch, w1, w2, w3,
                                            b1, g1, be1, m1, v1,
                                            b2, g2, be2, m2, v2,
                                            b3, g3, be3, m3, v3,
                                            btg, bnsc, bnsh, cursor, psum, gcnt,
                                            flags);
    passA_k<<<PASSA_WG, 256, 0, stream>>>(ei, flags, cursor, pairs);
    passB_k<<<NBK, 256, 0, stream>>>(pairs, cursor, offs, degcnt, dinv, csr);

    const int ggrid = (NN + 63) / 64;          // 1563 (covers row NN sentinel too)
    const int agrid = NN / 4;                  // 25000

    gemm_mfma_k<true><<<ggrid, 256, 0, stream>>>(x_in, nullptr, btg, dinv, hpre, NN);
    aggregate_k<<<agrid, 256, 0, stream>>>(hpre, csr, offs, degcnt, dinv,
                                           bnsc, bnsh, bufx);
    gemm_mfma_k<false><<<ggrid, 256, 0, stream>>>(nullptr, bufx, btg + 8192, dinv, hpre, NN);
    aggregate_k<<<agrid, 256, 0, stream>>>(hpre, csr, offs, degcnt, dinv,
                                           bnsc + 128, bnsh + 128, bufx);
    gemm_mfma_k<false><<<ggrid, 256, 0, stream>>>(nullptr, bufx, btg + 16384, dinv, hpre, NN);
    aggregate_k<<<agrid, 256, 0, stream>>>(hpre, csr, offs, degcnt, dinv,
                                           bnsc + 256, bnsh + 256, bufx);

    pool_sum_k<<<ggrid, 256, 0, stream>>>(bufx, batch, flags, psum, gcnt);
    head_k<<<GG, 128, 0, stream>>>(psum, gcnt, fw1, fb1, fw2, fb2, out);
}

// Round 12
// 462.187 us; speedup vs baseline: 1.0017x; 1.0017x over previous
//
#include <hip/hip_runtime.h>
#include <math.h>

#define NN 100000
#define EE 1600000
#define GG 256
#define HH 128
#define BSH 8                 /* 256 nodes per bucket */
#define NBK 391               /* ceil(NN/256) */
#define PASSA_WG 391          /* r10-proven: 16 edges/thread */
#define CAPB 6144             /* per-bucket region: edges(~4092) + self/pad8(<=2048) */

typedef __attribute__((ext_vector_type(8))) short short8;   // 8 bf16 (4 VGPRs)
typedef __attribute__((ext_vector_type(4))) float f32x4;    // MFMA acc

union U4S8 { uint4 u; short8 s; };

// ---------------------------------------------------------------------------
// bf16 helpers (RNE pack, cheap unpack)
// ---------------------------------------------------------------------------
static __device__ __forceinline__ unsigned bf16rne(float f) {
    const unsigned u = __float_as_uint(f);
    return (u + 0x7fffu + ((u >> 16) & 1u)) >> 16;
}
static __device__ __forceinline__ unsigned packbf(float a, float b) {
    return bf16rne(a) | (bf16rne(b) << 16);
}
static __device__ __forceinline__ float bflo(unsigned u) { return __uint_as_float(u << 16); }
static __device__ __forceinline__ float bfhi(unsigned u) { return __uint_as_float(u & 0xffff0000u); }

// ---------------------------------------------------------------------------
// Fused setup: wprep (ids 0..24575), bnprep (..24703), cursinit (..25094),
// psum zero (..57862), gcnt zero (..58118), dtype detect (id 58119).
// ---------------------------------------------------------------------------
__global__ __launch_bounds__(256) void setup_k(
    const int* __restrict__ ei, const int* __restrict__ batch,
    const float* __restrict__ w1, const float* __restrict__ w2,
    const float* __restrict__ w3,
    const float* __restrict__ b1, const float* __restrict__ g1,
    const float* __restrict__ be1, const float* __restrict__ m1,
    const float* __restrict__ v1,
    const float* __restrict__ b2, const float* __restrict__ g2,
    const float* __restrict__ be2, const float* __restrict__ m2,
    const float* __restrict__ v2,
    const float* __restrict__ b3, const float* __restrict__ g3,
    const float* __restrict__ be3, const float* __restrict__ m3,
    const float* __restrict__ v3,
    unsigned* __restrict__ bt, float* __restrict__ sc, float* __restrict__ sh,
    int* __restrict__ cursor, float* __restrict__ psum, int* __restrict__ gcnt,
    int* __restrict__ flags) {
    const int id = blockIdx.x * 256 + threadIdx.x;
    if (id < 24576) {
        const int w = id >> 13;
        const int rem = id & 8191;
        const int n = rem >> 6;
        const int kk = rem & 63;                      // k-pair
        const float* W = (w == 0) ? w1 : (w == 1) ? w2 : w3;
        bt[id] = packbf(W[(2 * kk) * HH + n], W[(2 * kk + 1) * HH + n]);
    } else if (id < 24704) {
        const int c = id - 24576;
        float s;
        s = g1[c] / sqrtf(v1[c] + 1e-5f);
        sc[c] = s;           sh[c] = (b1[c] - m1[c]) * s + be1[c];
        s = g2[c] / sqrtf(v2[c] + 1e-5f);
        sc[128 + c] = s;     sh[128 + c] = (b2[c] - m2[c]) * s + be2[c];
        s = g3[c] / sqrtf(v3[c] + 1e-5f);
        sc[256 + c] = s;     sh[256 + c] = (b3[c] - m3[c]) * s + be3[c];
    } else if (id < 25095) {
        const int b = id - 24704;
        cursor[b] = b * CAPB;
    } else if (id < 57863) {
        psum[id - 25095] = 0.0f;
    } else if (id < 58119) {
        gcnt[id - 57863] = 0;
    } else if (id == 58119) {
        int e64 = 1;
        for (int j = 0; j < 8; ++j) {
            if (ei[2 * EE - 1 - 2 * j] != 0) { e64 = 0; break; }
        }
        flags[0] = e64;
        flags[1] = (batch[NN - 1] == 0) ? 1 : 0;
    }
}
#define SETUP_GRID 228   /* ceil(58120/256) */

// ---------------------------------------------------------------------------
// pass A (r10 config): 391 wgs x 4096 edges (16/thread), bucket-grouped
// packed-pair scatter into fixed regions. packed = (dloc<<17) | src
// ---------------------------------------------------------------------------
__global__ __launch_bounds__(256) void passA_k(const int* __restrict__ ei,
                                               const int* __restrict__ flags,
                                               int* __restrict__ cursor,
                                               unsigned* __restrict__ pairs) {
    __shared__ int h[NBK];
    __shared__ int rbase[NBK];
    const int tid = threadIdx.x;
    for (int i = tid; i < NBK; i += 256) h[i] = 0;
    __syncthreads();
    const bool e64 = flags[0] != 0;
    const int base = blockIdx.x * 4096;
    int scache[16], dcache[16];
#pragma unroll
    for (int j = 0; j < 16; ++j) {
        const int e = base + j * 256 + tid;
        int s = -1, d = 0;
        if (e < EE) {
            s = e64 ? ei[2 * e] : ei[e];
            d = e64 ? ei[2 * (EE + e)] : ei[EE + e];
            atomicAdd(&h[d >> BSH], 1);
        }
        scache[j] = s; dcache[j] = d;
    }
    __syncthreads();
    for (int i = tid; i < NBK; i += 256) {
        const int c = h[i];
        rbase[i] = c ? atomicAdd(&cursor[i], c) : 0;
    }
    __syncthreads();
    for (int i = tid; i < NBK; i += 256) h[i] = 0;
    __syncthreads();
#pragma unroll
    for (int j = 0; j < 16; ++j) {
        const int s = scache[j];
        if (s >= 0) {
            const int d = dcache[j];
            const int b = d >> BSH;
            const int r = atomicAdd(&h[b], 1);
            pairs[rbase[b] + r] = ((unsigned)(d & 255) << 17) | (unsigned)s;
        }
    }
}

// ---------------------------------------------------------------------------
// pass B: one wg per bucket -> offs/degcnt/dinv + bucketed CSR with
// self-inclusive padding to a multiple of 8 (sentinel NN = zero row).
// ---------------------------------------------------------------------------
__global__ __launch_bounds__(256) void passB_k(const unsigned* __restrict__ pairs,
                                               const int* __restrict__ cursor,
                                               int* __restrict__ offs,
                                               int* __restrict__ degcnt,
                                               float* __restrict__ dinv,
                                               int* __restrict__ csr) {
    __shared__ unsigned pk[CAPB];
    __shared__ int cnt[256];
    __shared__ int loff[256];
    __shared__ int sc[256];
    const int tid = threadIdx.x;
    const int b = blockIdx.x;
    const int p0 = b * CAPB;
    const int np = cursor[b] - p0;           // real edges in bucket
    const int nb0 = b << BSH;
    const int nnode = (NN - nb0 < 256) ? (NN - nb0) : 256;

    cnt[tid] = 0;
    __syncthreads();
    for (int i = tid; i < np; i += 256) {
        const unsigned p = pairs[p0 + i];
        pk[i] = p;
        atomicAdd(&cnt[p >> 17], 1);
    }
    __syncthreads();
    const int creal = cnt[tid];
    const int cpad = (tid < nnode) ? ((creal + 8) & ~7) : 0;   // +self, pad to 8
    sc[tid] = cpad;
    __syncthreads();
    for (int off = 1; off < 256; off <<= 1) {
        int t = (tid >= off) ? sc[tid - off] : 0;
        __syncthreads();
        sc[tid] += t;
        __syncthreads();
    }
    const int ex = sc[tid] - cpad;
    loff[tid] = ex;
    if (tid < nnode) {
        const int node = nb0 + tid;
        offs[node] = p0 + ex;
        degcnt[node] = creal;
        dinv[node] = 1.0f / sqrtf((float)(creal + 1));
    }
    __syncthreads();
    cnt[tid] = 0;
    __syncthreads();
    for (int i = tid; i < np; i += 256) {
        const unsigned p = pk[i];
        const int dl = (int)(p >> 17);
        const int r = atomicAdd(&cnt[dl], 1);
        csr[p0 + loff[dl] + r] = (int)(p & 0x1FFFFu);
    }
    if (tid < nnode) {
        const int basep = p0 + loff[tid];
        csr[basep + creal] = nb0 + tid;
        for (int j = creal + 1; j < cpad; ++j) csr[basep + j] = NN;
    }
}

// ---------------------------------------------------------------------------
// Hybrid MFMA bf16 GEMM (LDS-staged B^T + direct C^T stores), verified r10.
// Row M (sentinel) is written as zeros. dinv row-scale fused.
// ---------------------------------------------------------------------------
static __device__ __forceinline__ float sani(float v) {
    if (isnan(v)) return 0.0f;
    if (isinf(v)) return v > 0.0f ? 1e6f : -1e6f;
    return v;
}

template <bool AF32>
__global__ __launch_bounds__(256) void gemm_mfma_k(const float* __restrict__ Af,
                                                   const unsigned* __restrict__ Abf,
                                                   const unsigned* __restrict__ btg,
                                                   const float* __restrict__ dinv,
                                                   unsigned* __restrict__ C, int M) {
    __shared__ unsigned lds_u[8704];   // B^T: 128 rows x 68 uints (34816 B)
    const int tid = threadIdx.x;
    const int wave = tid >> 6;
    const int lane = tid & 63;
    const int nl = lane & 15;
    const int q = lane >> 4;
    const int row0 = blockIdx.x * 64 + wave * 16;
    const int rowg = row0 + nl;
    const int rowa = min(rowg, M - 1);

    // stage B^T: 128 rows x 64 uints (btg) -> LDS rows of 68 uints
    {
        const uint4* __restrict__ bg4 = (const uint4*)btg;
        for (int i = tid; i < 2048; i += 256) {
            const int n = i >> 4, w4 = i & 15;
            *(uint4*)&lds_u[n * 68 + w4 * 4] = bg4[n * 16 + w4];
        }
    }

    // B-operand = A rows: lane holds A[rowa][ks*32 + q*8 .. +7], 4 k-steps
    short8 a[4];
    if (AF32) {
#pragma unroll
        for (int ks = 0; ks < 4; ++ks) {
            const float4 p = *(const float4*)(Af + (size_t)rowa * HH + ks * 32 + q * 8);
            const float4 r = *(const float4*)(Af + (size_t)rowa * HH + ks * 32 + q * 8 + 4);
            U4S8 cv;
            cv.u = make_uint4(packbf(sani(p.x), sani(p.y)), packbf(sani(p.z), sani(p.w)),
                              packbf(sani(r.x), sani(r.y)), packbf(sani(r.z), sani(r.w)));
            a[ks] = cv.s;
        }
    } else {
#pragma unroll
        for (int ks = 0; ks < 4; ++ks) {
            U4S8 cv;
            cv.u = *(const uint4*)(Abf + (size_t)rowa * 64 + ks * 16 + q * 4);
            a[ks] = cv.s;
        }
    }

    __syncthreads();   // B^T staged

    f32x4 acc[8];
#pragma unroll
    for (int t = 0; t < 8; ++t) acc[t] = (f32x4)0.0f;

    const unsigned short* __restrict__ bts = (const unsigned short*)lds_u;
#pragma unroll
    for (int ks = 0; ks < 4; ++ks) {
#pragma unroll
        for (int t = 0; t < 8; ++t) {
            const int n = t * 16 + nl;
            const short8 b = *(const short8*)(bts + n * 136 + ks * 32 + q * 8);
            acc[t] = __builtin_amdgcn_mfma_f32_16x16x32_bf16(b, a[ks], acc[t], 0, 0, 0);
        }
    }

    // store C^T fragments: lane holds channels t*16 + q*4 + (0..3) of node rowg
    if (rowg < M) {
        const float dsc = dinv[rowg];
        unsigned* crow = C + (size_t)rowg * 64;
#pragma unroll
        for (int t = 0; t < 8; ++t) {
            uint2 o;
            o.x = packbf(dsc * acc[t][0], dsc * acc[t][1]);
            o.y = packbf(dsc * acc[t][2], dsc * acc[t][3]);
            *(uint2*)(crow + t * 8 + q * 2) = o;
        }
    } else if (rowg == M) {
        unsigned* crow = C + (size_t)M * 64;
#pragma unroll
        for (int t = 0; t < 8; ++t)
            *(uint2*)(crow + t * 8 + q * 2) = make_uint2(0u, 0u);
    }
}

// ---------------------------------------------------------------------------
// Fused aggregate + BN(eval) + ReLU over pre-scaled rows; bf16 in/out.
// Critical-path-collapsed: the first 32 list slots' indices are loaded in
// one round (sentinel NN where e >= npad; predicate is wave-uniform since
// npad % 8 == 0), then all 8 gathers issue together. 96% of nodes
// (npad <= 32) finish with zero loop iterations; rare heavy nodes use the
// 16-wide loop for the remainder.
// ---------------------------------------------------------------------------
__global__ __launch_bounds__(256) void aggregate_k(
    const unsigned* __restrict__ hpre, const int* __restrict__ csr,
    const int* __restrict__ offs, const int* __restrict__ cnt,
    const float* __restrict__ dinv,
    const float* __restrict__ bnsc, const float* __restrict__ bnsh,
    unsigned* __restrict__ xout) {
    const int v = __builtin_amdgcn_readfirstlane(blockIdx.x * 4 + (threadIdx.x >> 6));
    const int lane = threadIdx.x & 63;
    const int cg = lane & 15;
    const int sub = lane >> 4;
    const int c8 = cg * 8;

    const float dv = dinv[v];
    const int start = offs[v];
    const int npad = (cnt[v] + 8) & ~7;      // +self, padded to x8 (matches passB)
    const char* __restrict__ hb = (const char*)hpre;   // row = 256 B
    const unsigned cgo = (unsigned)(cg << 4);

    float acc[8];
#pragma unroll
    for (int j = 0; j < 8; ++j) acc[j] = 0.0f;

    // one round of index loads for slots 0..31 (sentinel beyond npad)
    int idx[8];
#pragma unroll
    for (int j = 0; j < 8; ++j) {
        const int e = j * 4 + sub;
        idx[j] = (e < npad) ? csr[start + e] : NN;
    }
    // one round of gathers (sentinel row = zeros, L1-hot)
    uint4 r[8];
#pragma unroll
    for (int j = 0; j < 8; ++j)
        r[j] = *(const uint4*)(hb + (((unsigned)idx[j] << 8) | cgo));
#pragma unroll
    for (int j = 0; j < 8; ++j) {
        acc[0] += bflo(r[j].x); acc[1] += bfhi(r[j].x);
        acc[2] += bflo(r[j].y); acc[3] += bfhi(r[j].y);
        acc[4] += bflo(r[j].z); acc[5] += bfhi(r[j].z);
        acc[6] += bflo(r[j].w); acc[7] += bfhi(r[j].w);
    }

    if (npad > 32) {                          // rare heavy nodes (~4%)
        int i = 32;
        for (; i + 16 <= npad; i += 16) {
            const int sA = csr[start + i + sub];
            const int sB = csr[start + i + 4 + sub];
            const int sC = csr[start + i + 8 + sub];
            const int sD = csr[start + i + 12 + sub];
            const uint4 rA = *(const uint4*)(hb + (((unsigned)sA << 8) | cgo));
            const uint4 rB = *(const uint4*)(hb + (((unsigned)sB << 8) | cgo));
            const uint4 rC = *(const uint4*)(hb + (((unsigned)sC << 8) | cgo));
            const uint4 rD = *(const uint4*)(hb + (((unsigned)sD << 8) | cgo));
            acc[0] += (bflo(rA.x) + bflo(rB.x)) + (bflo(rC.x) + bflo(rD.x));
            acc[1] += (bfhi(rA.x) + bfhi(rB.x)) + (bfhi(rC.x) + bfhi(rD.x));
            acc[2] += (bflo(rA.y) + bflo(rB.y)) + (bflo(rC.y) + bflo(rD.y));
            acc[3] += (bfhi(rA.y) + bfhi(rB.y)) + (bfhi(rC.y) + bfhi(rD.y));
            acc[4] += (bflo(rA.z) + bflo(rB.z)) + (bflo(rC.z) + bflo(rD.z));
            acc[5] += (bfhi(rA.z) + bfhi(rB.z)) + (bfhi(rC.z) + bfhi(rD.z));
            acc[6] += (bflo(rA.w) + bflo(rB.w)) + (bflo(rC.w) + bflo(rD.w));
            acc[7] += (bfhi(rA.w) + bfhi(rB.w)) + (bfhi(rC.w) + bfhi(rD.w));
        }
        if (i < npad) {                       // wave-uniform tail of exactly 8
            const int sA = csr[start + i + sub];
            const int sB = csr[start + i + 4 + sub];
            const uint4 rA = *(const uint4*)(hb + (((unsigned)sA << 8) | cgo));
            const uint4 rB = *(const uint4*)(hb + (((unsigned)sB << 8) | cgo));
            acc[0] += bflo(rA.x) + bflo(rB.x);
            acc[1] += bfhi(rA.x) + bfhi(rB.x);
            acc[2] += bflo(rA.y) + bflo(rB.y);
            acc[3] += bfhi(rA.y) + bfhi(rB.y);
            acc[4] += bflo(rA.z) + bflo(rB.z);
            acc[5] += bfhi(rA.z) + bfhi(rB.z);
            acc[6] += bflo(rA.w) + bflo(rB.w);
            acc[7] += bfhi(rA.w) + bfhi(rB.w);
        }
    }

#pragma unroll
    for (int j = 0; j < 8; ++j) {
        acc[j] += __shfl_xor(acc[j], 16);
        acc[j] += __shfl_xor(acc[j], 32);
    }

    if (sub == 0) {
        const float4 sca = *(const float4*)(bnsc + c8);
        const float4 scb = *(const float4*)(bnsc + c8 + 4);
        const float4 sha = *(const float4*)(bnsh + c8);
        const float4 shb = *(const float4*)(bnsh + c8 + 4);
        const float y0 = fmaxf(dv * acc[0] * sca.x + sha.x, 0.0f);
        const float y1 = fmaxf(dv * acc[1] * sca.y + sha.y, 0.0f);
        const float y2 = fmaxf(dv * acc[2] * sca.z + sha.z, 0.0f);
        const float y3 = fmaxf(dv * acc[3] * sca.w + sha.w, 0.0f);
        const float y4 = fmaxf(dv * acc[4] * scb.x + shb.x, 0.0f);
        const float y5 = fmaxf(dv * acc[5] * scb.y + shb.y, 0.0f);
        const float y6 = fmaxf(dv * acc[6] * scb.z + shb.z, 0.0f);
        const float y7 = fmaxf(dv * acc[7] * scb.w + shb.w, 0.0f);
        *(uint4*)(xout + (size_t)v * 64 + cg * 4) =
            make_uint4(packbf(y0, y1), packbf(y2, y3), packbf(y4, y5), packbf(y6, y7));
    }
}

// ---------------------------------------------------------------------------
// Parallel mean-pool, phase 1: per-wave 16-row run accumulation + boundary
// atomics into psum[g][128] (f32) and gcnt[g]. batch is sorted.
// ---------------------------------------------------------------------------
__global__ __launch_bounds__(256) void pool_sum_k(
    const unsigned* __restrict__ x, const int* __restrict__ batch,
    const int* __restrict__ flags, float* __restrict__ psum,
    int* __restrict__ gcnt) {
    const int wave = threadIdx.x >> 6;
    const int lane = threadIdx.x & 63;
    const int row0 = blockIdx.x * 64 + wave * 16;
    if (row0 >= NN) return;
    const bool b64 = flags[1] != 0;

    float sx = 0.0f, sy = 0.0f;
    int cur = -1, runlen = 0;
#pragma unroll
    for (int r = 0; r < 16; ++r) {
        const int row = row0 + r;
        if (row >= NN) break;
        const int g = b64 ? batch[2 * row] : batch[row];
        if (g != cur) {
            if (cur >= 0) {
                atomicAdd(&psum[cur * HH + lane * 2 + 0], sx);
                atomicAdd(&psum[cur * HH + lane * 2 + 1], sy);
                if (lane == 0) atomicAdd(&gcnt[cur], runlen);
            }
            cur = g; sx = 0.0f; sy = 0.0f; runlen = 0;
        }
        const unsigned u = x[(size_t)row * 64 + lane];
        sx += bflo(u);
        sy += bfhi(u);
        ++runlen;
    }
    if (cur >= 0) {
        atomicAdd(&psum[cur * HH + lane * 2 + 0], sx);
        atomicAdd(&psum[cur * HH + lane * 2 + 1], sy);
        if (lane == 0) atomicAdd(&gcnt[cur], runlen);
    }
}

// ---------------------------------------------------------------------------
// Head: pooled = psum/cnt, then fc1+ReLU+fc2. One block per graph.
// ---------------------------------------------------------------------------
__global__ __launch_bounds__(128) void head_k(
    const float* __restrict__ psum, const int* __restrict__ gcnt,
    const float* __restrict__ fw1, const float* __restrict__ fb1,
    const float* __restrict__ fw2, const float* __restrict__ fb2,
    float* __restrict__ out) {
    __shared__ float pooled[128];
    __shared__ float hid[64];
    const int g = blockIdx.x;
    const int tid = threadIdx.x;

    const int cntn = gcnt[g];
    pooled[tid] = psum[g * HH + tid] / (float)(cntn > 0 ? cntn : 1);
    __syncthreads();

    if (tid < 64) {
        float a = fb1[tid];
#pragma unroll 4
        for (int k = 0; k < 128; ++k) a += pooled[k] * fw1[k * 64 + tid];
        hid[tid] = fmaxf(a, 0.0f);
    }
    __syncthreads();
    if (tid < 10) {
        float a = fb2[tid];
#pragma unroll
        for (int k = 0; k < 64; ++k) a += hid[k] * fw2[k * 10 + tid];
        out[g * 10 + tid] = a;
    }
}

// ---------------------------------------------------------------------------
// launch
// ---------------------------------------------------------------------------
extern "C" void kernel_launch(void* const* d_in, const int* in_sizes, int n_in,
                              void* d_out, int out_size, void* d_ws, size_t ws_size,
                              hipStream_t stream) {
    const float* x_in  = (const float*)d_in[0];
    const int*   ei    = (const int*)d_in[1];
    const int*   batch = (const int*)d_in[2];
    const float* w1 = (const float*)d_in[3];
    const float* b1 = (const float*)d_in[4];
    const float* w2 = (const float*)d_in[5];
    const float* b2 = (const float*)d_in[6];
    const float* w3 = (const float*)d_in[7];
    const float* b3 = (const float*)d_in[8];
    const float* g1 = (const float*)d_in[9];
    const float* be1 = (const float*)d_in[10];
    const float* m1 = (const float*)d_in[11];
    const float* v1 = (const float*)d_in[12];
    const float* g2 = (const float*)d_in[13];
    const float* be2 = (const float*)d_in[14];
    const float* m2 = (const float*)d_in[15];
    const float* v2 = (const float*)d_in[16];
    const float* g3 = (const float*)d_in[17];
    const float* be3 = (const float*)d_in[18];
    const float* m3 = (const float*)d_in[19];
    const float* v3 = (const float*)d_in[20];
    const float* fw1 = (const float*)d_in[21];
    const float* fb1 = (const float*)d_in[22];
    const float* fw2 = (const float*)d_in[23];
    const float* fb2 = (const float*)d_in[24];
    float* out = (float*)d_out;

    size_t off = 0;
    char* base = (char*)d_ws;
    auto alloc = [&](size_t bytes) -> void* {
        void* p = base + off;
        off += (bytes + 255) & ~(size_t)255;
        return p;
    };
    int*      degcnt = (int*)alloc((size_t)NN * 4);
    float*    dinv   = (float*)alloc((size_t)NN * 4);
    int*      offs   = (int*)alloc((size_t)NN * 4);
    int*      cursor = (int*)alloc((size_t)NBK * 4);
    int*      flags  = (int*)alloc(256);
    float*    bnsc   = (float*)alloc(3 * 128 * 4);
    float*    bnsh   = (float*)alloc(3 * 128 * 4);
    unsigned* btg    = (unsigned*)alloc(3 * 8192 * 4);            // bf16 B^T x3
    float*    psum   = (float*)alloc((size_t)GG * HH * 4);        // pooled sums f32
    int*      gcnt   = (int*)alloc((size_t)GG * 4);
    int*      csr    = (int*)alloc((size_t)NBK * CAPB * 4);
    unsigned* pairs  = (unsigned*)alloc((size_t)NBK * CAPB * 4);
    unsigned* bufx   = (unsigned*)alloc((size_t)NN * 64 * 4);         // bf16 x2 packed
    unsigned* hpre   = (unsigned*)alloc((size_t)(NN + 1) * 64 * 4);   // + sentinel row
    if (off > ws_size) return;

    setup_k<<<SETUP_GRID, 256, 0, stream>>>(ei, batch, w1, w2, w3,
                                            b1, g1, be1, m1, v1,
                                            b2, g2, be2, m2, v2,
                                            b3, g3, be3, m3, v3,
                                            btg, bnsc, bnsh, cursor, psum, gcnt,
                                            flags);
    passA_k<<<PASSA_WG, 256, 0, stream>>>(ei, flags, cursor, pairs);
    passB_k<<<NBK, 256, 0, stream>>>(pairs, cursor, offs, degcnt, dinv, csr);

    const int ggrid = (NN + 63) / 64;          // 1563 (covers row NN sentinel too)
    const int agrid = NN / 4;                  // 25000

    gemm_mfma_k<true><<<ggrid, 256, 0, stream>>>(x_in, nullptr, btg, dinv, hpre, NN);
    aggregate_k<<<agrid, 256, 0, stream>>>(hpre, csr, offs, degcnt, dinv,
                                           bnsc, bnsh, bufx);
    gemm_mfma_k<false><<<ggrid, 256, 0, stream>>>(nullptr, bufx, btg + 8192, dinv, hpre, NN);
    aggregate_k<<<agrid, 256, 0, stream>>>(hpre, csr, offs, degcnt, dinv,
                                           bnsc + 128, bnsh + 128, bufx);
    gemm_mfma_k<false><<<ggrid, 256, 0, stream>>>(nullptr, bufx, btg + 16384, dinv, hpre, NN);
    aggregate_k<<<agrid, 256, 0, stream>>>(hpre, csr, offs, degcnt, dinv,
                                           bnsc + 256, bnsh + 256, bufx);

    pool_sum_k<<<ggrid, 256, 0, stream>>>(bufx, batch, flags, psum, gcnt);
    head_k<<<GG, 128, 0, stream>>>(psum, gcnt, fw1, fb1, fw2, fb2, out);
}

// Round 13
// 440.316 us; speedup vs baseline: 1.0514x; 1.0497x over previous
//
#include <hip/hip_runtime.h>
#include <math.h>

#define NN 100000
#define EE 1600000
#define GG 256
#define HH 128
#define BSH 8                 /* 256 nodes per bucket */
#define NBK 391               /* ceil(NN/256) */
#define PASSA_WG 391          /* r10-proven: 16 edges/thread */
#define CAPB 6144             /* per-bucket region: edges(~4092) + self/pad8(<=2048) */

typedef __attribute__((ext_vector_type(8))) short short8;   // 8 bf16 (4 VGPRs)
typedef __attribute__((ext_vector_type(4))) float f32x4;    // MFMA acc

union U4S8 { uint4 u; short8 s; };

// ---------------------------------------------------------------------------
// bf16 helpers (RNE pack, cheap unpack)
// ---------------------------------------------------------------------------
static __device__ __forceinline__ unsigned bf16rne(float f) {
    const unsigned u = __float_as_uint(f);
    return (u + 0x7fffu + ((u >> 16) & 1u)) >> 16;
}
static __device__ __forceinline__ unsigned packbf(float a, float b) {
    return bf16rne(a) | (bf16rne(b) << 16);
}
static __device__ __forceinline__ float bflo(unsigned u) { return __uint_as_float(u << 16); }
static __device__ __forceinline__ float bfhi(unsigned u) { return __uint_as_float(u & 0xffff0000u); }

// ---------------------------------------------------------------------------
// Fused setup: wprep (ids 0..24575), bnprep (..24703), cursinit (..25094),
// psum zero (..57862), gcnt zero (..58118), dtype detect (id 58119).
// Ledger r10->r12: this merge is worth ~-11 us vs separate launches.
// ---------------------------------------------------------------------------
__global__ __launch_bounds__(256) void setup_k(
    const int* __restrict__ ei, const int* __restrict__ batch,
    const float* __restrict__ w1, const float* __restrict__ w2,
    const float* __restrict__ w3,
    const float* __restrict__ b1, const float* __restrict__ g1,
    const float* __restrict__ be1, const float* __restrict__ m1,
    const float* __restrict__ v1,
    const float* __restrict__ b2, const float* __restrict__ g2,
    const float* __restrict__ be2, const float* __restrict__ m2,
    const float* __restrict__ v2,
    const float* __restrict__ b3, const float* __restrict__ g3,
    const float* __restrict__ be3, const float* __restrict__ m3,
    const float* __restrict__ v3,
    unsigned* __restrict__ bt, float* __restrict__ sc, float* __restrict__ sh,
    int* __restrict__ cursor, float* __restrict__ psum, int* __restrict__ gcnt,
    int* __restrict__ flags) {
    const int id = blockIdx.x * 256 + threadIdx.x;
    if (id < 24576) {
        const int w = id >> 13;
        const int rem = id & 8191;
        const int n = rem >> 6;
        const int kk = rem & 63;                      // k-pair
        const float* W = (w == 0) ? w1 : (w == 1) ? w2 : w3;
        bt[id] = packbf(W[(2 * kk) * HH + n], W[(2 * kk + 1) * HH + n]);
    } else if (id < 24704) {
        const int c = id - 24576;
        float s;
        s = g1[c] / sqrtf(v1[c] + 1e-5f);
        sc[c] = s;           sh[c] = (b1[c] - m1[c]) * s + be1[c];
        s = g2[c] / sqrtf(v2[c] + 1e-5f);
        sc[128 + c] = s;     sh[128 + c] = (b2[c] - m2[c]) * s + be2[c];
        s = g3[c] / sqrtf(v3[c] + 1e-5f);
        sc[256 + c] = s;     sh[256 + c] = (b3[c] - m3[c]) * s + be3[c];
    } else if (id < 25095) {
        const int b = id - 24704;
        cursor[b] = b * CAPB;
    } else if (id < 57863) {
        psum[id - 25095] = 0.0f;
    } else if (id < 58119) {
        gcnt[id - 57863] = 0;
    } else if (id == 58119) {
        int e64 = 1;
        for (int j = 0; j < 8; ++j) {
            if (ei[2 * EE - 1 - 2 * j] != 0) { e64 = 0; break; }
        }
        flags[0] = e64;
        flags[1] = (batch[NN - 1] == 0) ? 1 : 0;
    }
}
#define SETUP_GRID 228   /* ceil(58120/256) */

// ---------------------------------------------------------------------------
// pass A (r10 config): 391 wgs x 4096 edges (16/thread), bucket-grouped
// packed-pair scatter into fixed regions. packed = (dloc<<17) | src
// Ledger: 1563-wg regrid (r11) cost +28 us — per-block histogram fixed costs
// dominate; this shape already has enough ILP. Do not regrid.
// ---------------------------------------------------------------------------
__global__ __launch_bounds__(256) void passA_k(const int* __restrict__ ei,
                                               const int* __restrict__ flags,
                                               int* __restrict__ cursor,
                                               unsigned* __restrict__ pairs) {
    __shared__ int h[NBK];
    __shared__ int rbase[NBK];
    const int tid = threadIdx.x;
    for (int i = tid; i < NBK; i += 256) h[i] = 0;
    __syncthreads();
    const bool e64 = flags[0] != 0;
    const int base = blockIdx.x * 4096;
    int scache[16], dcache[16];
#pragma unroll
    for (int j = 0; j < 16; ++j) {
        const int e = base + j * 256 + tid;
        int s = -1, d = 0;
        if (e < EE) {
            s = e64 ? ei[2 * e] : ei[e];
            d = e64 ? ei[2 * (EE + e)] : ei[EE + e];
            atomicAdd(&h[d >> BSH], 1);
        }
        scache[j] = s; dcache[j] = d;
    }
    __syncthreads();
    for (int i = tid; i < NBK; i += 256) {
        const int c = h[i];
        rbase[i] = c ? atomicAdd(&cursor[i], c) : 0;
    }
    __syncthreads();
    for (int i = tid; i < NBK; i += 256) h[i] = 0;
    __syncthreads();
#pragma unroll
    for (int j = 0; j < 16; ++j) {
        const int s = scache[j];
        if (s >= 0) {
            const int d = dcache[j];
            const int b = d >> BSH;
            const int r = atomicAdd(&h[b], 1);
            pairs[rbase[b] + r] = ((unsigned)(d & 255) << 17) | (unsigned)s;
        }
    }
}

// ---------------------------------------------------------------------------
// pass B: one wg per bucket -> offs/degcnt/dinv + bucketed CSR with
// self-inclusive padding to a multiple of 8 (sentinel NN = zero row).
// ---------------------------------------------------------------------------
__global__ __launch_bounds__(256) void passB_k(const unsigned* __restrict__ pairs,
                                               const int* __restrict__ cursor,
                                               int* __restrict__ offs,
                                               int* __restrict__ degcnt,
                                               float* __restrict__ dinv,
                                               int* __restrict__ csr) {
    __shared__ unsigned pk[CAPB];
    __shared__ int cnt[256];
    __shared__ int loff[256];
    __shared__ int sc[256];
    const int tid = threadIdx.x;
    const int b = blockIdx.x;
    const int p0 = b * CAPB;
    const int np = cursor[b] - p0;           // real edges in bucket
    const int nb0 = b << BSH;
    const int nnode = (NN - nb0 < 256) ? (NN - nb0) : 256;

    cnt[tid] = 0;
    __syncthreads();
    for (int i = tid; i < np; i += 256) {
        const unsigned p = pairs[p0 + i];
        pk[i] = p;
        atomicAdd(&cnt[p >> 17], 1);
    }
    __syncthreads();
    const int creal = cnt[tid];
    const int cpad = (tid < nnode) ? ((creal + 8) & ~7) : 0;   // +self, pad to 8
    sc[tid] = cpad;
    __syncthreads();
    for (int off = 1; off < 256; off <<= 1) {
        int t = (tid >= off) ? sc[tid - off] : 0;
        __syncthreads();
        sc[tid] += t;
        __syncthreads();
    }
    const int ex = sc[tid] - cpad;
    loff[tid] = ex;
    if (tid < nnode) {
        const int node = nb0 + tid;
        offs[node] = p0 + ex;
        degcnt[node] = creal;
        dinv[node] = 1.0f / sqrtf((float)(creal + 1));
    }
    __syncthreads();
    cnt[tid] = 0;
    __syncthreads();
    for (int i = tid; i < np; i += 256) {
        const unsigned p = pk[i];
        const int dl = (int)(p >> 17);
        const int r = atomicAdd(&cnt[dl], 1);
        csr[p0 + loff[dl] + r] = (int)(p & 0x1FFFFu);
    }
    if (tid < nnode) {
        const int basep = p0 + loff[tid];
        csr[basep + creal] = nb0 + tid;
        for (int j = creal + 1; j < cpad; ++j) csr[basep + j] = NN;
    }
}

// ---------------------------------------------------------------------------
// Hybrid MFMA bf16 GEMM (LDS-staged B^T + direct C^T stores), verified r10.
// Row M (sentinel) is written as zeros. dinv row-scale fused.
// ---------------------------------------------------------------------------
static __device__ __forceinline__ float sani(float v) {
    if (isnan(v)) return 0.0f;
    if (isinf(v)) return v > 0.0f ? 1e6f : -1e6f;
    return v;
}

template <bool AF32>
__global__ __launch_bounds__(256) void gemm_mfma_k(const float* __restrict__ Af,
                                                   const unsigned* __restrict__ Abf,
                                                   const unsigned* __restrict__ btg,
                                                   const float* __restrict__ dinv,
                                                   unsigned* __restrict__ C, int M) {
    __shared__ unsigned lds_u[8704];   // B^T: 128 rows x 68 uints (34816 B)
    const int tid = threadIdx.x;
    const int wave = tid >> 6;
    const int lane = tid & 63;
    const int nl = lane & 15;
    const int q = lane >> 4;
    const int row0 = blockIdx.x * 64 + wave * 16;
    const int rowg = row0 + nl;
    const int rowa = min(rowg, M - 1);

    // stage B^T: 128 rows x 64 uints (btg) -> LDS rows of 68 uints
    {
        const uint4* __restrict__ bg4 = (const uint4*)btg;
        for (int i = tid; i < 2048; i += 256) {
            const int n = i >> 4, w4 = i & 15;
            *(uint4*)&lds_u[n * 68 + w4 * 4] = bg4[n * 16 + w4];
        }
    }

    // B-operand = A rows: lane holds A[rowa][ks*32 + q*8 .. +7], 4 k-steps
    short8 a[4];
    if (AF32) {
#pragma unroll
        for (int ks = 0; ks < 4; ++ks) {
            const float4 p = *(const float4*)(Af + (size_t)rowa * HH + ks * 32 + q * 8);
            const float4 r = *(const float4*)(Af + (size_t)rowa * HH + ks * 32 + q * 8 + 4);
            U4S8 cv;
            cv.u = make_uint4(packbf(sani(p.x), sani(p.y)), packbf(sani(p.z), sani(p.w)),
                              packbf(sani(r.x), sani(r.y)), packbf(sani(r.z), sani(r.w)));
            a[ks] = cv.s;
        }
    } else {
#pragma unroll
        for (int ks = 0; ks < 4; ++ks) {
            U4S8 cv;
            cv.u = *(const uint4*)(Abf + (size_t)rowa * 64 + ks * 16 + q * 4);
            a[ks] = cv.s;
        }
    }

    __syncthreads();   // B^T staged

    f32x4 acc[8];
#pragma unroll
    for (int t = 0; t < 8; ++t) acc[t] = (f32x4)0.0f;

    const unsigned short* __restrict__ bts = (const unsigned short*)lds_u;
#pragma unroll
    for (int ks = 0; ks < 4; ++ks) {
#pragma unroll
        for (int t = 0; t < 8; ++t) {
            const int n = t * 16 + nl;
            const short8 b = *(const short8*)(bts + n * 136 + ks * 32 + q * 8);
            acc[t] = __builtin_amdgcn_mfma_f32_16x16x32_bf16(b, a[ks], acc[t], 0, 0, 0);
        }
    }

    // store C^T fragments: lane holds channels t*16 + q*4 + (0..3) of node rowg
    if (rowg < M) {
        const float dsc = dinv[rowg];
        unsigned* crow = C + (size_t)rowg * 64;
#pragma unroll
        for (int t = 0; t < 8; ++t) {
            uint2 o;
            o.x = packbf(dsc * acc[t][0], dsc * acc[t][1]);
            o.y = packbf(dsc * acc[t][2], dsc * acc[t][3]);
            *(uint2*)(crow + t * 8 + q * 2) = o;
        }
    } else if (rowg == M) {
        unsigned* crow = C + (size_t)M * 64;
#pragma unroll
        for (int t = 0; t < 8; ++t)
            *(uint2*)(crow + t * 8 + q * 2) = make_uint2(0u, 0u);
    }
}

// ---------------------------------------------------------------------------
// Fused aggregate + BN(eval) + ReLU over pre-scaled rows; bf16 in/out.
// r10-verified version (59.5 us, VGPR 28): 16 entries/iter (4 gathers in
// flight), wave-uniform 8-tail. The r12 flat-32 prefetch variant regressed
// (+9.5 us: ~30% wasted sentinel gathers + VGPR pressure) — keep this one.
// ---------------------------------------------------------------------------
__global__ __launch_bounds__(256) void aggregate_k(
    const unsigned* __restrict__ hpre, const int* __restrict__ csr,
    const int* __restrict__ offs, const int* __restrict__ cnt,
    const float* __restrict__ dinv,
    const float* __restrict__ bnsc, const float* __restrict__ bnsh,
    unsigned* __restrict__ xout) {
    const int v = __builtin_amdgcn_readfirstlane(blockIdx.x * 4 + (threadIdx.x >> 6));
    const int lane = threadIdx.x & 63;
    const int cg = lane & 15;
    const int sub = lane >> 4;
    const int c8 = cg * 8;

    const float dv = dinv[v];
    const int start = offs[v];
    const int npad = (cnt[v] + 8) & ~7;      // +self, padded to x8 (matches passB)
    const char* __restrict__ hb = (const char*)hpre;   // row = 256 B
    const unsigned cgo = (unsigned)(cg << 4);

    float acc[8];
#pragma unroll
    for (int j = 0; j < 8; ++j) acc[j] = 0.0f;

    int i = 0;
    for (; i + 16 <= npad; i += 16) {        // 16 entries/iter: 4 gathers in flight
        const int sA = csr[start + i + sub];
        const int sB = csr[start + i + 4 + sub];
        const int sC = csr[start + i + 8 + sub];
        const int sD = csr[start + i + 12 + sub];
        const uint4 rA = *(const uint4*)(hb + (((unsigned)sA << 8) | cgo));
        const uint4 rB = *(const uint4*)(hb + (((unsigned)sB << 8) | cgo));
        const uint4 rC = *(const uint4*)(hb + (((unsigned)sC << 8) | cgo));
        const uint4 rD = *(const uint4*)(hb + (((unsigned)sD << 8) | cgo));
        acc[0] += (bflo(rA.x) + bflo(rB.x)) + (bflo(rC.x) + bflo(rD.x));
        acc[1] += (bfhi(rA.x) + bfhi(rB.x)) + (bfhi(rC.x) + bfhi(rD.x));
        acc[2] += (bflo(rA.y) + bflo(rB.y)) + (bflo(rC.y) + bflo(rD.y));
        acc[3] += (bfhi(rA.y) + bfhi(rB.y)) + (bfhi(rC.y) + bfhi(rD.y));
        acc[4] += (bflo(rA.z) + bflo(rB.z)) + (bflo(rC.z) + bflo(rD.z));
        acc[5] += (bfhi(rA.z) + bfhi(rB.z)) + (bfhi(rC.z) + bfhi(rD.z));
        acc[6] += (bflo(rA.w) + bflo(rB.w)) + (bflo(rC.w) + bflo(rD.w));
        acc[7] += (bfhi(rA.w) + bfhi(rB.w)) + (bfhi(rC.w) + bfhi(rD.w));
    }
    if (i < npad) {                          // wave-uniform tail of exactly 8
        const int sA = csr[start + i + sub];
        const int sB = csr[start + i + 4 + sub];
        const uint4 rA = *(const uint4*)(hb + (((unsigned)sA << 8) | cgo));
        const uint4 rB = *(const uint4*)(hb + (((unsigned)sB << 8) | cgo));
        acc[0] += bflo(rA.x) + bflo(rB.x);
        acc[1] += bfhi(rA.x) + bfhi(rB.x);
        acc[2] += bflo(rA.y) + bflo(rB.y);
        acc[3] += bfhi(rA.y) + bfhi(rB.y);
        acc[4] += bflo(rA.z) + bflo(rB.z);
        acc[5] += bfhi(rA.z) + bfhi(rB.z);
        acc[6] += bflo(rA.w) + bflo(rB.w);
        acc[7] += bfhi(rA.w) + bfhi(rB.w);
    }

#pragma unroll
    for (int j = 0; j < 8; ++j) {
        acc[j] += __shfl_xor(acc[j], 16);
        acc[j] += __shfl_xor(acc[j], 32);
    }

    if (sub == 0) {
        const float4 sca = *(const float4*)(bnsc + c8);
        const float4 scb = *(const float4*)(bnsc + c8 + 4);
        const float4 sha = *(const float4*)(bnsh + c8);
        const float4 shb = *(const float4*)(bnsh + c8 + 4);
        const float y0 = fmaxf(dv * acc[0] * sca.x + sha.x, 0.0f);
        const float y1 = fmaxf(dv * acc[1] * sca.y + sha.y, 0.0f);
        const float y2 = fmaxf(dv * acc[2] * sca.z + sha.z, 0.0f);
        const float y3 = fmaxf(dv * acc[3] * sca.w + sha.w, 0.0f);
        const float y4 = fmaxf(dv * acc[4] * scb.x + shb.x, 0.0f);
        const float y5 = fmaxf(dv * acc[5] * scb.y + shb.y, 0.0f);
        const float y6 = fmaxf(dv * acc[6] * scb.z + shb.z, 0.0f);
        const float y7 = fmaxf(dv * acc[7] * scb.w + shb.w, 0.0f);
        *(uint4*)(xout + (size_t)v * 64 + cg * 4) =
            make_uint4(packbf(y0, y1), packbf(y2, y3), packbf(y4, y5), packbf(y6, y7));
    }
}

// ---------------------------------------------------------------------------
// Parallel mean-pool, phase 1: per-wave 16-row run accumulation + boundary
// atomics into psum[g][128] (f32) and gcnt[g]. batch is sorted.
// ---------------------------------------------------------------------------
__global__ __launch_bounds__(256) void pool_sum_k(
    const unsigned* __restrict__ x, const int* __restrict__ batch,
    const int* __restrict__ flags, float* __restrict__ psum,
    int* __restrict__ gcnt) {
    const int wave = threadIdx.x >> 6;
    const int lane = threadIdx.x & 63;
    const int row0 = blockIdx.x * 64 + wave * 16;
    if (row0 >= NN) return;
    const bool b64 = flags[1] != 0;

    float sx = 0.0f, sy = 0.0f;
    int cur = -1, runlen = 0;
#pragma unroll
    for (int r = 0; r < 16; ++r) {
        const int row = row0 + r;
        if (row >= NN) break;
        const int g = b64 ? batch[2 * row] : batch[row];
        if (g != cur) {
            if (cur >= 0) {
                atomicAdd(&psum[cur * HH + lane * 2 + 0], sx);
                atomicAdd(&psum[cur * HH + lane * 2 + 1], sy);
                if (lane == 0) atomicAdd(&gcnt[cur], runlen);
            }
            cur = g; sx = 0.0f; sy = 0.0f; runlen = 0;
        }
        const unsigned u = x[(size_t)row * 64 + lane];
        sx += bflo(u);
        sy += bfhi(u);
        ++runlen;
    }
    if (cur >= 0) {
        atomicAdd(&psum[cur * HH + lane * 2 + 0], sx);
        atomicAdd(&psum[cur * HH + lane * 2 + 1], sy);
        if (lane == 0) atomicAdd(&gcnt[cur], runlen);
    }
}

// ---------------------------------------------------------------------------
// Head: pooled = psum/cnt, then fc1+ReLU+fc2. One block per graph.
// ---------------------------------------------------------------------------
__global__ __launch_bounds__(128) void head_k(
    const float* __restrict__ psum, const int* __restrict__ gcnt,
    const float* __restrict__ fw1, const float* __restrict__ fb1,
    const float* __restrict__ fw2, const float* __restrict__ fb2,
    float* __restrict__ out) {
    __shared__ float pooled[128];
    __shared__ float hid[64];
    const int g = blockIdx.x;
    const int tid = threadIdx.x;

    const int cntn = gcnt[g];
    pooled[tid] = psum[g * HH + tid] / (float)(cntn > 0 ? cntn : 1);
    __syncthreads();

    if (tid < 64) {
        float a = fb1[tid];
#pragma unroll 4
        for (int k = 0; k < 128; ++k) a += pooled[k] * fw1[k * 64 + tid];
        hid[tid] = fmaxf(a, 0.0f);
    }
    __syncthreads();
    if (tid < 10) {
        float a = fb2[tid];
#pragma unroll
        for (int k = 0; k < 64; ++k) a += hid[k] * fw2[k * 10 + tid];
        out[g * 10 + tid] = a;
    }
}

// ---------------------------------------------------------------------------
// launch
// ---------------------------------------------------------------------------
extern "C" void kernel_launch(void* const* d_in, const int* in_sizes, int n_in,
                              void* d_out, int out_size, void* d_ws, size_t ws_size,
                              hipStream_t stream) {
    const float* x_in  = (const float*)d_in[0];
    const int*   ei    = (const int*)d_in[1];
    const int*   batch = (const int*)d_in[2];
    const float* w1 = (const float*)d_in[3];
    const float* b1 = (const float*)d_in[4];
    const float* w2 = (const float*)d_in[5];
    const float* b2 = (const float*)d_in[6];
    const float* w3 = (const float*)d_in[7];
    const float* b3 = (const float*)d_in[8];
    const float* g1 = (const float*)d_in[9];
    const float* be1 = (const float*)d_in[10];
    const float* m1 = (const float*)d_in[11];
    const float* v1 = (const float*)d_in[12];
    const float* g2 = (const float*)d_in[13];
    const float* be2 = (const float*)d_in[14];
    const float* m2 = (const float*)d_in[15];
    const float* v2 = (const float*)d_in[16];
    const float* g3 = (const float*)d_in[17];
    const float* be3 = (const float*)d_in[18];
    const float* m3 = (const float*)d_in[19];
    const float* v3 = (const float*)d_in[20];
    const float* fw1 = (const float*)d_in[21];
    const float* fb1 = (const float*)d_in[22];
    const float* fw2 = (const float*)d_in[23];
    const float* fb2 = (const float*)d_in[24];
    float* out = (float*)d_out;

    size_t off = 0;
    char* base = (char*)d_ws;
    auto alloc = [&](size_t bytes) -> void* {
        void* p = base + off;
        off += (bytes + 255) & ~(size_t)255;
        return p;
    };
    int*      degcnt = (int*)alloc((size_t)NN * 4);
    float*    dinv   = (float*)alloc((size_t)NN * 4);
    int*      offs   = (int*)alloc((size_t)NN * 4);
    int*      cursor = (int*)alloc((size_t)NBK * 4);
    int*      flags  = (int*)alloc(256);
    float*    bnsc   = (float*)alloc(3 * 128 * 4);
    float*    bnsh   = (float*)alloc(3 * 128 * 4);
    unsigned* btg    = (unsigned*)alloc(3 * 8192 * 4);            // bf16 B^T x3
    float*    psum   = (float*)alloc((size_t)GG * HH * 4);        // pooled sums f32
    int*      gcnt   = (int*)alloc((size_t)GG * 4);
    int*      csr    = (int*)alloc((size_t)NBK * CAPB * 4);
    unsigned* pairs  = (unsigned*)alloc((size_t)NBK * CAPB * 4);
    unsigned* bufx   = (unsigned*)alloc((size_t)NN * 64 * 4);         // bf16 x2 packed
    unsigned* hpre   = (unsigned*)alloc((size_t)(NN + 1) * 64 * 4);   // + sentinel row
    if (off > ws_size) return;

    setup_k<<<SETUP_GRID, 256, 0, stream>>>(ei, batch, w1, w2, w3,
                                            b1, g1, be1, m1, v1,
                                            b2, g2, be2, m2, v2,
                                            b3, g3, be3, m3, v3,
                                            btg, bnsc, bnsh, cursor, psum, gcnt,
                                            flags);
    passA_k<<<PASSA_WG, 256, 0, stream>>>(ei, flags, cursor, pairs);
    passB_k<<<NBK, 256, 0, stream>>>(pairs, cursor, offs, degcnt, dinv, csr);

    const int ggrid = (NN + 63) / 64;          // 1563 (covers row NN sentinel too)
    const int agrid = NN / 4;                  // 25000

    gemm_mfma_k<true><<<ggrid, 256, 0, stream>>>(x_in, nullptr, btg, dinv, hpre, NN);
    aggregate_k<<<agrid, 256, 0, stream>>>(hpre, csr, offs, degcnt, dinv,
                                           bnsc, bnsh, bufx);
    gemm_mfma_k<false><<<ggrid, 256, 0, stream>>>(nullptr, bufx, btg + 8192, dinv, hpre, NN);
    aggregate_k<<<agrid, 256, 0, stream>>>(hpre, csr, offs, degcnt, dinv,
                                           bnsc + 128, bnsh + 128, bufx);
    gemm_mfma_k<false><<<ggrid, 256, 0, stream>>>(nullptr, bufx, btg + 16384, dinv, hpre, NN);
    aggregate_k<<<agrid, 256, 0, stream>>>(hpre, csr, offs, degcnt, dinv,
                                           bnsc + 256, bnsh + 256, bufx);

    pool_sum_k<<<ggrid, 256, 0, stream>>>(bufx, batch, flags, psum, gcnt);
    head_k<<<GG, 128, 0, stream>>>(psum, gcnt, fw1, fb1, fw2, fb2, out);
}

// Round 14
// 435.941 us; speedup vs baseline: 1.0620x; 1.0100x over previous
//
#include <hip/hip_runtime.h>
#include <math.h>

#define NN 100000
#define EE 1600000
#define GG 256
#define HH 128
#define BSH 8                 /* 256 nodes per bucket */
#define NBK 391               /* ceil(NN/256) */
#define PASSA_WG 391          /* r10-proven: 16 edges/thread */
#define CAPB 6144             /* per-bucket region: edges(~4092) + self/pad8(<=2048) */

typedef __attribute__((ext_vector_type(8))) short short8;   // 8 bf16 (4 VGPRs)
typedef __attribute__((ext_vector_type(4))) float f32x4;    // MFMA acc

union U4S8 { uint4 u; short8 s; };

// ---------------------------------------------------------------------------
// bf16 helpers (RNE pack, cheap unpack)
// ---------------------------------------------------------------------------
static __device__ __forceinline__ unsigned bf16rne(float f) {
    const unsigned u = __float_as_uint(f);
    return (u + 0x7fffu + ((u >> 16) & 1u)) >> 16;
}
static __device__ __forceinline__ unsigned packbf(float a, float b) {
    return bf16rne(a) | (bf16rne(b) << 16);
}
static __device__ __forceinline__ float bflo(unsigned u) { return __uint_as_float(u << 16); }
static __device__ __forceinline__ float bfhi(unsigned u) { return __uint_as_float(u & 0xffff0000u); }

// ---------------------------------------------------------------------------
// Fused setup: wprep (ids 0..24575), bnprep (..24703), cursinit (..25094),
// psum zero (..57862), gcnt zero (..58118), dtype detect (id 58119).
// Ledger r10->r12: this merge is worth ~-11 us vs separate launches.
// ---------------------------------------------------------------------------
__global__ __launch_bounds__(256) void setup_k(
    const int* __restrict__ ei, const int* __restrict__ batch,
    const float* __restrict__ w1, const float* __restrict__ w2,
    const float* __restrict__ w3,
    const float* __restrict__ b1, const float* __restrict__ g1,
    const float* __restrict__ be1, const float* __restrict__ m1,
    const float* __restrict__ v1,
    const float* __restrict__ b2, const float* __restrict__ g2,
    const float* __restrict__ be2, const float* __restrict__ m2,
    const float* __restrict__ v2,
    const float* __restrict__ b3, const float* __restrict__ g3,
    const float* __restrict__ be3, const float* __restrict__ m3,
    const float* __restrict__ v3,
    unsigned* __restrict__ bt, float* __restrict__ sc, float* __restrict__ sh,
    int* __restrict__ cursor, float* __restrict__ psum, int* __restrict__ gcnt,
    int* __restrict__ flags) {
    const int id = blockIdx.x * 256 + threadIdx.x;
    if (id < 24576) {
        const int w = id >> 13;
        const int rem = id & 8191;
        const int n = rem >> 6;
        const int kk = rem & 63;                      // k-pair
        const float* W = (w == 0) ? w1 : (w == 1) ? w2 : w3;
        bt[id] = packbf(W[(2 * kk) * HH + n], W[(2 * kk + 1) * HH + n]);
    } else if (id < 24704) {
        const int c = id - 24576;
        float s;
        s = g1[c] / sqrtf(v1[c] + 1e-5f);
        sc[c] = s;           sh[c] = (b1[c] - m1[c]) * s + be1[c];
        s = g2[c] / sqrtf(v2[c] + 1e-5f);
        sc[128 + c] = s;     sh[128 + c] = (b2[c] - m2[c]) * s + be2[c];
        s = g3[c] / sqrtf(v3[c] + 1e-5f);
        sc[256 + c] = s;     sh[256 + c] = (b3[c] - m3[c]) * s + be3[c];
    } else if (id < 25095) {
        const int b = id - 24704;
        cursor[b] = b * CAPB;
    } else if (id < 57863) {
        psum[id - 25095] = 0.0f;
    } else if (id < 58119) {
        gcnt[id - 57863] = 0;
    } else if (id == 58119) {
        int e64 = 1;
        for (int j = 0; j < 8; ++j) {
            if (ei[2 * EE - 1 - 2 * j] != 0) { e64 = 0; break; }
        }
        flags[0] = e64;
        flags[1] = (batch[NN - 1] == 0) ? 1 : 0;
    }
}
#define SETUP_GRID 228   /* ceil(58120/256) */

// ---------------------------------------------------------------------------
// pass A (r10 config): 391 wgs x 4096 edges (16/thread). Do not regrid
// (r11 ledger: 1563-wg version cost +28 us on per-block histogram overhead).
// ---------------------------------------------------------------------------
__global__ __launch_bounds__(256) void passA_k(const int* __restrict__ ei,
                                               const int* __restrict__ flags,
                                               int* __restrict__ cursor,
                                               unsigned* __restrict__ pairs) {
    __shared__ int h[NBK];
    __shared__ int rbase[NBK];
    const int tid = threadIdx.x;
    for (int i = tid; i < NBK; i += 256) h[i] = 0;
    __syncthreads();
    const bool e64 = flags[0] != 0;
    const int base = blockIdx.x * 4096;
    int scache[16], dcache[16];
#pragma unroll
    for (int j = 0; j < 16; ++j) {
        const int e = base + j * 256 + tid;
        int s = -1, d = 0;
        if (e < EE) {
            s = e64 ? ei[2 * e] : ei[e];
            d = e64 ? ei[2 * (EE + e)] : ei[EE + e];
            atomicAdd(&h[d >> BSH], 1);
        }
        scache[j] = s; dcache[j] = d;
    }
    __syncthreads();
    for (int i = tid; i < NBK; i += 256) {
        const int c = h[i];
        rbase[i] = c ? atomicAdd(&cursor[i], c) : 0;
    }
    __syncthreads();
    for (int i = tid; i < NBK; i += 256) h[i] = 0;
    __syncthreads();
#pragma unroll
    for (int j = 0; j < 16; ++j) {
        const int s = scache[j];
        if (s >= 0) {
            const int d = dcache[j];
            const int b = d >> BSH;
            const int r = atomicAdd(&h[b], 1);
            pairs[rbase[b] + r] = ((unsigned)(d & 255) << 17) | (unsigned)s;
        }
    }
}

// ---------------------------------------------------------------------------
// pass B: one wg per bucket -> offs/degcnt/dinv + bucketed CSR with
// self-inclusive padding to a multiple of 8 (sentinel NN = zero row).
// ---------------------------------------------------------------------------
__global__ __launch_bounds__(256) void passB_k(const unsigned* __restrict__ pairs,
                                               const int* __restrict__ cursor,
                                               int* __restrict__ offs,
                                               int* __restrict__ degcnt,
                                               float* __restrict__ dinv,
                                               int* __restrict__ csr) {
    __shared__ unsigned pk[CAPB];
    __shared__ int cnt[256];
    __shared__ int loff[256];
    __shared__ int sc[256];
    const int tid = threadIdx.x;
    const int b = blockIdx.x;
    const int p0 = b * CAPB;
    const int np = cursor[b] - p0;           // real edges in bucket
    const int nb0 = b << BSH;
    const int nnode = (NN - nb0 < 256) ? (NN - nb0) : 256;

    cnt[tid] = 0;
    __syncthreads();
    for (int i = tid; i < np; i += 256) {
        const unsigned p = pairs[p0 + i];
        pk[i] = p;
        atomicAdd(&cnt[p >> 17], 1);
    }
    __syncthreads();
    const int creal = cnt[tid];
    const int cpad = (tid < nnode) ? ((creal + 8) & ~7) : 0;   // +self, pad to 8
    sc[tid] = cpad;
    __syncthreads();
    for (int off = 1; off < 256; off <<= 1) {
        int t = (tid >= off) ? sc[tid - off] : 0;
        __syncthreads();
        sc[tid] += t;
        __syncthreads();
    }
    const int ex = sc[tid] - cpad;
    loff[tid] = ex;
    if (tid < nnode) {
        const int node = nb0 + tid;
        offs[node] = p0 + ex;
        degcnt[node] = creal;
        dinv[node] = 1.0f / sqrtf((float)(creal + 1));
    }
    __syncthreads();
    cnt[tid] = 0;
    __syncthreads();
    for (int i = tid; i < np; i += 256) {
        const unsigned p = pk[i];
        const int dl = (int)(p >> 17);
        const int r = atomicAdd(&cnt[dl], 1);
        csr[p0 + loff[dl] + r] = (int)(p & 0x1FFFFu);
    }
    if (tid < nnode) {
        const int basep = p0 + loff[tid];
        csr[basep + creal] = nb0 + tid;
        for (int j = creal + 1; j < cpad; ++j) csr[basep + j] = NN;
    }
}

// ---------------------------------------------------------------------------
// Hybrid MFMA bf16 GEMM (LDS-staged B^T + direct C^T stores), verified r10.
// Used only for layer 1 (f32 input x). Row M sentinel zeroed; dinv fused.
// ---------------------------------------------------------------------------
static __device__ __forceinline__ float sani(float v) {
    if (isnan(v)) return 0.0f;
    if (isinf(v)) return v > 0.0f ? 1e6f : -1e6f;
    return v;
}

__global__ __launch_bounds__(256) void gemm_mfma_k(const float* __restrict__ Af,
                                                   const unsigned* __restrict__ btg,
                                                   const float* __restrict__ dinv,
                                                   unsigned* __restrict__ C, int M) {
    __shared__ unsigned lds_u[8704];   // B^T: 128 rows x 68 uints (34816 B)
    const int tid = threadIdx.x;
    const int wave = tid >> 6;
    const int lane = tid & 63;
    const int nl = lane & 15;
    const int q = lane >> 4;
    const int row0 = blockIdx.x * 64 + wave * 16;
    const int rowg = row0 + nl;
    const int rowa = min(rowg, M - 1);

    {
        const uint4* __restrict__ bg4 = (const uint4*)btg;
        for (int i = tid; i < 2048; i += 256) {
            const int n = i >> 4, w4 = i & 15;
            *(uint4*)&lds_u[n * 68 + w4 * 4] = bg4[n * 16 + w4];
        }
    }

    short8 a[4];
#pragma unroll
    for (int ks = 0; ks < 4; ++ks) {
        const float4 p = *(const float4*)(Af + (size_t)rowa * HH + ks * 32 + q * 8);
        const float4 r = *(const float4*)(Af + (size_t)rowa * HH + ks * 32 + q * 8 + 4);
        U4S8 cv;
        cv.u = make_uint4(packbf(sani(p.x), sani(p.y)), packbf(sani(p.z), sani(p.w)),
                          packbf(sani(r.x), sani(r.y)), packbf(sani(r.z), sani(r.w)));
        a[ks] = cv.s;
    }

    __syncthreads();   // B^T staged

    f32x4 acc[8];
#pragma unroll
    for (int t = 0; t < 8; ++t) acc[t] = (f32x4)0.0f;

    const unsigned short* __restrict__ bts = (const unsigned short*)lds_u;
#pragma unroll
    for (int ks = 0; ks < 4; ++ks) {
#pragma unroll
        for (int t = 0; t < 8; ++t) {
            const int n = t * 16 + nl;
            const short8 b = *(const short8*)(bts + n * 136 + ks * 32 + q * 8);
            acc[t] = __builtin_amdgcn_mfma_f32_16x16x32_bf16(b, a[ks], acc[t], 0, 0, 0);
        }
    }

    if (rowg < M) {
        const float dsc = dinv[rowg];
        unsigned* crow = C + (size_t)rowg * 64;
#pragma unroll
        for (int t = 0; t < 8; ++t) {
            uint2 o;
            o.x = packbf(dsc * acc[t][0], dsc * acc[t][1]);
            o.y = packbf(dsc * acc[t][2], dsc * acc[t][3]);
            *(uint2*)(crow + t * 8 + q * 2) = o;
        }
    } else if (rowg == M) {
        unsigned* crow = C + (size_t)M * 64;
#pragma unroll
        for (int t = 0; t < 8; ++t)
            *(uint2*)(crow + t * 8 + q * 2) = make_uint2(0u, 0u);
    }
}

// ---------------------------------------------------------------------------
// FUSED aggregate(L) + gemm(L+1): block = 4 waves x 4 nodes/wave = 16 nodes.
// Gather phase identical to r10-verified aggregate_k (16 entries/iter, 4 in
// flight, wave-uniform 8-tail); y rows (bf16) staged in 4.4 KB LDS; then
// each wave MFMAs 2 channel-tiles x 16 rows against btg (8 direct fragment
// loads from L2 — used once, latency amortized) and stores C^T uint2 rows
// scaled by dinv (next layer's pre-scaled gather table). Output sentinel
// row NN zeroed by block 0. Numerics bit-identical to the unfused pipeline.
// ---------------------------------------------------------------------------
__global__ __launch_bounds__(256) void agg_gemm_k(
    const unsigned* __restrict__ hin, const int* __restrict__ csr,
    const int* __restrict__ offs, const int* __restrict__ cnt,
    const float* __restrict__ dinv,
    const float* __restrict__ bnsc, const float* __restrict__ bnsh,
    const unsigned* __restrict__ btg,
    unsigned* __restrict__ hout) {
    __shared__ unsigned ybuf[16 * 68];
    const int tid = threadIdx.x;
    const int wave = tid >> 6;
    const int lane = tid & 63;
    const int cg = lane & 15;
    const int sub = lane >> 4;
    const int c8 = cg * 8;
    const char* __restrict__ hb = (const char*)hin;
    const unsigned cgo = (unsigned)(cg << 4);

    if (blockIdx.x == 0 && tid < 64) hout[(size_t)NN * 64 + tid] = 0u;

    const float4 sca = *(const float4*)(bnsc + c8);
    const float4 scb = *(const float4*)(bnsc + c8 + 4);
    const float4 sha = *(const float4*)(bnsh + c8);
    const float4 shb = *(const float4*)(bnsh + c8 + 4);

    for (int i = 0; i < 4; ++i) {
        const int v = __builtin_amdgcn_readfirstlane(blockIdx.x * 16 + wave * 4 + i);
        const float dv = dinv[v];
        const int start = offs[v];
        const int npad = (cnt[v] + 8) & ~7;

        float acc[8];
#pragma unroll
        for (int j = 0; j < 8; ++j) acc[j] = 0.0f;

        int e = 0;
        for (; e + 16 <= npad; e += 16) {
            const int sA = csr[start + e + sub];
            const int sB = csr[start + e + 4 + sub];
            const int sC = csr[start + e + 8 + sub];
            const int sD = csr[start + e + 12 + sub];
            const uint4 rA = *(const uint4*)(hb + (((unsigned)sA << 8) | cgo));
            const uint4 rB = *(const uint4*)(hb + (((unsigned)sB << 8) | cgo));
            const uint4 rC = *(const uint4*)(hb + (((unsigned)sC << 8) | cgo));
            const uint4 rD = *(const uint4*)(hb + (((unsigned)sD << 8) | cgo));
            acc[0] += (bflo(rA.x) + bflo(rB.x)) + (bflo(rC.x) + bflo(rD.x));
            acc[1] += (bfhi(rA.x) + bfhi(rB.x)) + (bfhi(rC.x) + bfhi(rD.x));
            acc[2] += (bflo(rA.y) + bflo(rB.y)) + (bflo(rC.y) + bflo(rD.y));
            acc[3] += (bfhi(rA.y) + bfhi(rB.y)) + (bfhi(rC.y) + bfhi(rD.y));
            acc[4] += (bflo(rA.z) + bflo(rB.z)) + (bflo(rC.z) + bflo(rD.z));
            acc[5] += (bfhi(rA.z) + bfhi(rB.z)) + (bfhi(rC.z) + bfhi(rD.z));
            acc[6] += (bflo(rA.w) + bflo(rB.w)) + (bflo(rC.w) + bflo(rD.w));
            acc[7] += (bfhi(rA.w) + bfhi(rB.w)) + (bfhi(rC.w) + bfhi(rD.w));
        }
        if (e < npad) {
            const int sA = csr[start + e + sub];
            const int sB = csr[start + e + 4 + sub];
            const uint4 rA = *(const uint4*)(hb + (((unsigned)sA << 8) | cgo));
            const uint4 rB = *(const uint4*)(hb + (((unsigned)sB << 8) | cgo));
            acc[0] += bflo(rA.x) + bflo(rB.x);
            acc[1] += bfhi(rA.x) + bfhi(rB.x);
            acc[2] += bflo(rA.y) + bflo(rB.y);
            acc[3] += bfhi(rA.y) + bfhi(rB.y);
            acc[4] += bflo(rA.z) + bflo(rB.z);
            acc[5] += bfhi(rA.z) + bfhi(rB.z);
            acc[6] += bflo(rA.w) + bflo(rB.w);
            acc[7] += bfhi(rA.w) + bfhi(rB.w);
        }

#pragma unroll
        for (int j = 0; j < 8; ++j) {
            acc[j] += __shfl_xor(acc[j], 16);
            acc[j] += __shfl_xor(acc[j], 32);
        }

        if (sub == 0) {
            const float y0 = fmaxf(dv * acc[0] * sca.x + sha.x, 0.0f);
            const float y1 = fmaxf(dv * acc[1] * sca.y + sha.y, 0.0f);
            const float y2 = fmaxf(dv * acc[2] * sca.z + sha.z, 0.0f);
            const float y3 = fmaxf(dv * acc[3] * sca.w + sha.w, 0.0f);
            const float y4 = fmaxf(dv * acc[4] * scb.x + shb.x, 0.0f);
            const float y5 = fmaxf(dv * acc[5] * scb.y + shb.y, 0.0f);
            const float y6 = fmaxf(dv * acc[6] * scb.z + shb.z, 0.0f);
            const float y7 = fmaxf(dv * acc[7] * scb.w + shb.w, 0.0f);
            *(uint4*)&ybuf[(wave * 4 + i) * 68 + cg * 4] =
                make_uint4(packbf(y0, y1), packbf(y2, y3), packbf(y4, y5), packbf(y6, y7));
        }
    }
    __syncthreads();

    // gemm tail: wave computes channel tiles t0=2*wave, t0+1 for all 16 rows
    const int nl = cg;     // row selector within block
    const int q = sub;     // k-quad
    short8 arow[4];
#pragma unroll
    for (int ks = 0; ks < 4; ++ks) {
        U4S8 cv;
        cv.u = *(const uint4*)&ybuf[nl * 68 + ks * 16 + q * 4];
        arow[ks] = cv.s;
    }
    const uint4* __restrict__ bt4 = (const uint4*)btg;
    const int t0 = wave * 2;
    f32x4 acc0 = (f32x4)0.0f, acc1 = (f32x4)0.0f;
#pragma unroll
    for (int ks = 0; ks < 4; ++ks) {
        U4S8 b0, b1;
        b0.u = bt4[((t0 + 0) * 16 + nl) * 16 + ks * 4 + q];
        b1.u = bt4[((t0 + 1) * 16 + nl) * 16 + ks * 4 + q];
        acc0 = __builtin_amdgcn_mfma_f32_16x16x32_bf16(b0.s, arow[ks], acc0, 0, 0, 0);
        acc1 = __builtin_amdgcn_mfma_f32_16x16x32_bf16(b1.s, arow[ks], acc1, 0, 0, 0);
    }
    const int rowg = blockIdx.x * 16 + nl;
    const float dsc = dinv[rowg];
    unsigned* crow = hout + (size_t)rowg * 64;
    uint2 o0, o1;
    o0.x = packbf(dsc * acc0[0], dsc * acc0[1]);
    o0.y = packbf(dsc * acc0[2], dsc * acc0[3]);
    o1.x = packbf(dsc * acc1[0], dsc * acc1[1]);
    o1.y = packbf(dsc * acc1[2], dsc * acc1[3]);
    *(uint2*)(crow + (t0 + 0) * 8 + q * 2) = o0;
    *(uint2*)(crow + (t0 + 1) * 8 + q * 2) = o1;
}

// ---------------------------------------------------------------------------
// Layer-3 aggregate (standalone, r10-verified): gather + BN + ReLU -> bf16.
// ---------------------------------------------------------------------------
__global__ __launch_bounds__(256) void aggregate_k(
    const unsigned* __restrict__ hpre, const int* __restrict__ csr,
    const int* __restrict__ offs, const int* __restrict__ cnt,
    const float* __restrict__ dinv,
    const float* __restrict__ bnsc, const float* __restrict__ bnsh,
    unsigned* __restrict__ xout) {
    const int v = __builtin_amdgcn_readfirstlane(blockIdx.x * 4 + (threadIdx.x >> 6));
    const int lane = threadIdx.x & 63;
    const int cg = lane & 15;
    const int sub = lane >> 4;
    const int c8 = cg * 8;

    const float dv = dinv[v];
    const int start = offs[v];
    const int npad = (cnt[v] + 8) & ~7;
    const char* __restrict__ hb = (const char*)hpre;
    const unsigned cgo = (unsigned)(cg << 4);

    float acc[8];
#pragma unroll
    for (int j = 0; j < 8; ++j) acc[j] = 0.0f;

    int i = 0;
    for (; i + 16 <= npad; i += 16) {
        const int sA = csr[start + i + sub];
        const int sB = csr[start + i + 4 + sub];
        const int sC = csr[start + i + 8 + sub];
        const int sD = csr[start + i + 12 + sub];
        const uint4 rA = *(const uint4*)(hb + (((unsigned)sA << 8) | cgo));
        const uint4 rB = *(const uint4*)(hb + (((unsigned)sB << 8) | cgo));
        const uint4 rC = *(const uint4*)(hb + (((unsigned)sC << 8) | cgo));
        const uint4 rD = *(const uint4*)(hb + (((unsigned)sD << 8) | cgo));
        acc[0] += (bflo(rA.x) + bflo(rB.x)) + (bflo(rC.x) + bflo(rD.x));
        acc[1] += (bfhi(rA.x) + bfhi(rB.x)) + (bfhi(rC.x) + bfhi(rD.x));
        acc[2] += (bflo(rA.y) + bflo(rB.y)) + (bflo(rC.y) + bflo(rD.y));
        acc[3] += (bfhi(rA.y) + bfhi(rB.y)) + (bfhi(rC.y) + bfhi(rD.y));
        acc[4] += (bflo(rA.z) + bflo(rB.z)) + (bflo(rC.z) + bflo(rD.z));
        acc[5] += (bfhi(rA.z) + bfhi(rB.z)) + (bfhi(rC.z) + bfhi(rD.z));
        acc[6] += (bflo(rA.w) + bflo(rB.w)) + (bflo(rC.w) + bflo(rD.w));
        acc[7] += (bfhi(rA.w) + bfhi(rB.w)) + (bfhi(rC.w) + bfhi(rD.w));
    }
    if (i < npad) {
        const int sA = csr[start + i + sub];
        const int sB = csr[start + i + 4 + sub];
        const uint4 rA = *(const uint4*)(hb + (((unsigned)sA << 8) | cgo));
        const uint4 rB = *(const uint4*)(hb + (((unsigned)sB << 8) | cgo));
        acc[0] += bflo(rA.x) + bflo(rB.x);
        acc[1] += bfhi(rA.x) + bfhi(rB.x);
        acc[2] += bflo(rA.y) + bflo(rB.y);
        acc[3] += bfhi(rA.y) + bfhi(rB.y);
        acc[4] += bflo(rA.z) + bflo(rB.z);
        acc[5] += bfhi(rA.z) + bfhi(rB.z);
        acc[6] += bflo(rA.w) + bflo(rB.w);
        acc[7] += bfhi(rA.w) + bfhi(rB.w);
    }

#pragma unroll
    for (int j = 0; j < 8; ++j) {
        acc[j] += __shfl_xor(acc[j], 16);
        acc[j] += __shfl_xor(acc[j], 32);
    }

    if (sub == 0) {
        const float4 sca = *(const float4*)(bnsc + c8);
        const float4 scb = *(const float4*)(bnsc + c8 + 4);
        const float4 sha = *(const float4*)(bnsh + c8);
        const float4 shb = *(const float4*)(bnsh + c8 + 4);
        const float y0 = fmaxf(dv * acc[0] * sca.x + sha.x, 0.0f);
        const float y1 = fmaxf(dv * acc[1] * sca.y + sha.y, 0.0f);
        const float y2 = fmaxf(dv * acc[2] * sca.z + sha.z, 0.0f);
        const float y3 = fmaxf(dv * acc[3] * sca.w + sha.w, 0.0f);
        const float y4 = fmaxf(dv * acc[4] * scb.x + shb.x, 0.0f);
        const float y5 = fmaxf(dv * acc[5] * scb.y + shb.y, 0.0f);
        const float y6 = fmaxf(dv * acc[6] * scb.z + shb.z, 0.0f);
        const float y7 = fmaxf(dv * acc[7] * scb.w + shb.w, 0.0f);
        *(uint4*)(xout + (size_t)v * 64 + cg * 4) =
            make_uint4(packbf(y0, y1), packbf(y2, y3), packbf(y4, y5), packbf(y6, y7));
    }
}

// ---------------------------------------------------------------------------
// Parallel mean-pool, phase 1: per-wave 16-row run accumulation + boundary
// atomics into psum[g][128] (f32) and gcnt[g]. batch is sorted.
// ---------------------------------------------------------------------------
__global__ __launch_bounds__(256) void pool_sum_k(
    const unsigned* __restrict__ x, const int* __restrict__ batch,
    const int* __restrict__ flags, float* __restrict__ psum,
    int* __restrict__ gcnt) {
    const int wave = threadIdx.x >> 6;
    const int lane = threadIdx.x & 63;
    const int row0 = blockIdx.x * 64 + wave * 16;
    if (row0 >= NN) return;
    const bool b64 = flags[1] != 0;

    float sx = 0.0f, sy = 0.0f;
    int cur = -1, runlen = 0;
#pragma unroll
    for (int r = 0; r < 16; ++r) {
        const int row = row0 + r;
        if (row >= NN) break;
        const int g = b64 ? batch[2 * row] : batch[row];
        if (g != cur) {
            if (cur >= 0) {
                atomicAdd(&psum[cur * HH + lane * 2 + 0], sx);
                atomicAdd(&psum[cur * HH + lane * 2 + 1], sy);
                if (lane == 0) atomicAdd(&gcnt[cur], runlen);
            }
            cur = g; sx = 0.0f; sy = 0.0f; runlen = 0;
        }
        const unsigned u = x[(size_t)row * 64 + lane];
        sx += bflo(u);
        sy += bfhi(u);
        ++runlen;
    }
    if (cur >= 0) {
        atomicAdd(&psum[cur * HH + lane * 2 + 0], sx);
        atomicAdd(&psum[cur * HH + lane * 2 + 1], sy);
        if (lane == 0) atomicAdd(&gcnt[cur], runlen);
    }
}

// ---------------------------------------------------------------------------
// Head: pooled = psum/cnt, then fc1+ReLU+fc2. One block per graph.
// ---------------------------------------------------------------------------
__global__ __launch_bounds__(128) void head_k(
    const float* __restrict__ psum, const int* __restrict__ gcnt,
    const float* __restrict__ fw1, const float* __restrict__ fb1,
    const float* __restrict__ fw2, const float* __restrict__ fb2,
    float* __restrict__ out) {
    __shared__ float pooled[128];
    __shared__ float hid[64];
    const int g = blockIdx.x;
    const int tid = threadIdx.x;

    const int cntn = gcnt[g];
    pooled[tid] = psum[g * HH + tid] / (float)(cntn > 0 ? cntn : 1);
    __syncthreads();

    if (tid < 64) {
        float a = fb1[tid];
#pragma unroll 4
        for (int k = 0; k < 128; ++k) a += pooled[k] * fw1[k * 64 + tid];
        hid[tid] = fmaxf(a, 0.0f);
    }
    __syncthreads();
    if (tid < 10) {
        float a = fb2[tid];
#pragma unroll
        for (int k = 0; k < 64; ++k) a += hid[k] * fw2[k * 10 + tid];
        out[g * 10 + tid] = a;
    }
}

// ---------------------------------------------------------------------------
// launch
// ---------------------------------------------------------------------------
extern "C" void kernel_launch(void* const* d_in, const int* in_sizes, int n_in,
                              void* d_out, int out_size, void* d_ws, size_t ws_size,
                              hipStream_t stream) {
    const float* x_in  = (const float*)d_in[0];
    const int*   ei    = (const int*)d_in[1];
    const int*   batch = (const int*)d_in[2];
    const float* w1 = (const float*)d_in[3];
    const float* b1 = (const float*)d_in[4];
    const float* w2 = (const float*)d_in[5];
    const float* b2 = (const float*)d_in[6];
    const float* w3 = (const float*)d_in[7];
    const float* b3 = (const float*)d_in[8];
    const float* g1 = (const float*)d_in[9];
    const float* be1 = (const float*)d_in[10];
    const float* m1 = (const float*)d_in[11];
    const float* v1 = (const float*)d_in[12];
    const float* g2 = (const float*)d_in[13];
    const float* be2 = (const float*)d_in[14];
    const float* m2 = (const float*)d_in[15];
    const float* v2 = (const float*)d_in[16];
    const float* g3 = (const float*)d_in[17];
    const float* be3 = (const float*)d_in[18];
    const float* m3 = (const float*)d_in[19];
    const float* v3 = (const float*)d_in[20];
    const float* fw1 = (const float*)d_in[21];
    const float* fb1 = (const float*)d_in[22];
    const float* fw2 = (const float*)d_in[23];
    const float* fb2 = (const float*)d_in[24];
    float* out = (float*)d_out;

    size_t off = 0;
    char* base = (char*)d_ws;
    auto alloc = [&](size_t bytes) -> void* {
        void* p = base + off;
        off += (bytes + 255) & ~(size_t)255;
        return p;
    };
    int*      degcnt = (int*)alloc((size_t)NN * 4);
    float*    dinv   = (float*)alloc((size_t)NN * 4);
    int*      offs   = (int*)alloc((size_t)NN * 4);
    int*      cursor = (int*)alloc((size_t)NBK * 4);
    int*      flags  = (int*)alloc(256);
    float*    bnsc   = (float*)alloc(3 * 128 * 4);
    float*    bnsh   = (float*)alloc(3 * 128 * 4);
    unsigned* btg    = (unsigned*)alloc(3 * 8192 * 4);            // bf16 B^T x3
    float*    psum   = (float*)alloc((size_t)GG * HH * 4);        // pooled sums f32
    int*      gcnt   = (int*)alloc((size_t)GG * 4);
    int*      csr    = (int*)alloc((size_t)NBK * CAPB * 4);
    unsigned* pairs  = (unsigned*)alloc((size_t)NBK * CAPB * 4);
    unsigned* bufA   = (unsigned*)alloc((size_t)(NN + 1) * 64 * 4);   // + sentinel row
    unsigned* bufB   = (unsigned*)alloc((size_t)(NN + 1) * 64 * 4);   // + sentinel row
    if (off > ws_size) return;

    setup_k<<<SETUP_GRID, 256, 0, stream>>>(ei, batch, w1, w2, w3,
                                            b1, g1, be1, m1, v1,
                                            b2, g2, be2, m2, v2,
                                            b3, g3, be3, m3, v3,
                                            btg, bnsc, bnsh, cursor, psum, gcnt,
                                            flags);
    passA_k<<<PASSA_WG, 256, 0, stream>>>(ei, flags, cursor, pairs);
    passB_k<<<NBK, 256, 0, stream>>>(pairs, cursor, offs, degcnt, dinv, csr);

    const int ggrid = (NN + 63) / 64;          // 1563 (covers row NN sentinel too)
    const int fgrid = NN / 16;                 // 6250 (exact)
    const int agrid = NN / 4;                  // 25000

    // L1: x @ W1 -> bufA (dinv-scaled bf16 gather table)
    gemm_mfma_k<<<ggrid, 256, 0, stream>>>(x_in, btg, dinv, bufA, NN);
    // L1 aggregate + BN1 + ReLU fused with W2 gemm -> bufB
    agg_gemm_k<<<fgrid, 256, 0, stream>>>(bufA, csr, offs, degcnt, dinv,
                                          bnsc, bnsh, btg + 8192, bufB);
    // L2 aggregate + BN2 + ReLU fused with W3 gemm -> bufA
    agg_gemm_k<<<fgrid, 256, 0, stream>>>(bufB, csr, offs, degcnt, dinv,
                                          bnsc + 128, bnsh + 128, btg + 16384, bufA);
    // L3 aggregate + BN3 + ReLU -> bufB
    aggregate_k<<<agrid, 256, 0, stream>>>(bufA, csr, offs, degcnt, dinv,
                                           bnsc + 256, bnsh + 256, bufB);

    pool_sum_k<<<ggrid, 256, 0, stream>>>(bufB, batch, flags, psum, gcnt);
    head_k<<<GG, 128, 0, stream>>>(psum, gcnt, fw1, fb1, fw2, fb2, out);
}